// Round 10
// baseline (263.796 us; speedup 1.0000x reference)
//
#include <hip/hip_runtime.h>
#include <hip/hip_bf16.h>
#include <math.h>

// y[b,i] = sum_j x[b,j] * r[(j-i) mod N] + bias[i]
//        = circular conv: y = IFFT(FFT(x) * FFT(c)) + bias, c[k] = r[(-k) mod N]
// Radix-16 FFT route (N=4096 = 16^3): 3 fwd + 3 inv stages, fp32, in-LDS.
//   - two rows packed per FFT (z = x0 + i*x1), exact for real conv
//   - float4 global I/O routed through LDS (R9 lesson: scalar strided
//     global I/O caused 2.5x HBM traffic amplification)
//   - fused middle: F1 + pointwise(C) + I1 in registers
//   - NO twiddle gathers: per-thread base twiddle, powers by chained cmul
//   - PAD(i)=i+(i>>4)

#define NFFT 4096
#define PAD(i) ((i) + ((i) >> 4))

typedef __attribute__((ext_vector_type(4))) float f32x4;
typedef __attribute__((ext_vector_type(4))) unsigned short us4;

__device__ __forceinline__ float2 cadd(float2 a, float2 b) {
  return make_float2(a.x + b.x, a.y + b.y);
}
__device__ __forceinline__ float2 csub(float2 a, float2 b) {
  return make_float2(a.x - b.x, a.y - b.y);
}
__device__ __forceinline__ float2 cmul(float2 a, float2 b) {
  return make_float2(a.x * b.x - a.y * b.y, a.x * b.y + a.y * b.x);
}
__device__ __forceinline__ float2 cmulj(float2 a, float2 b) {  // a * conj(b)
  return make_float2(a.x * b.x + a.y * b.y, a.y * b.x - a.x * b.y);
}
__device__ __forceinline__ float2 mni(float2 a) {  // a * (-i)
  return make_float2(a.y, -a.x);
}
__device__ __forceinline__ float2 mpi(float2 a) {  // a * (+i)
  return make_float2(-a.y, a.x);
}

#define C1 0.9238795325112867f
#define S1 0.3826834323650898f
#define RQ 0.7071067811865476f

// natural-order DFT-16 (w = e^{-2pi i/16}): 4x4 decomposition.
__device__ __forceinline__ void fft16(float2 a[16]) {
  float2 G[4][4];
#pragma unroll
  for (int r = 0; r < 4; ++r) {
    float2 t0 = cadd(a[r], a[r + 8]);
    float2 t1 = csub(a[r], a[r + 8]);
    float2 t2 = cadd(a[r + 4], a[r + 12]);
    float2 t3 = csub(a[r + 4], a[r + 12]);
    G[r][0] = cadd(t0, t2);
    G[r][1] = cadd(t1, mni(t3));
    G[r][2] = csub(t0, t2);
    G[r][3] = cadd(t1, mpi(t3));
  }
  const float2 W1 = make_float2(C1, -S1);
  const float2 W2 = make_float2(RQ, -RQ);
  const float2 W3 = make_float2(S1, -C1);
  const float2 W6 = make_float2(-RQ, -RQ);
  const float2 W9 = make_float2(-C1, S1);
  G[1][1] = cmul(G[1][1], W1);
  G[1][2] = cmul(G[1][2], W2);
  G[1][3] = cmul(G[1][3], W3);
  G[2][1] = cmul(G[2][1], W2);
  G[2][2] = mni(G[2][2]);  // w^4 = -i
  G[2][3] = cmul(G[2][3], W6);
  G[3][1] = cmul(G[3][1], W3);
  G[3][2] = cmul(G[3][2], W6);
  G[3][3] = cmul(G[3][3], W9);
#pragma unroll
  for (int k1 = 0; k1 < 4; ++k1) {
    float2 t0 = cadd(G[0][k1], G[2][k1]);
    float2 t1 = csub(G[0][k1], G[2][k1]);
    float2 t2 = cadd(G[1][k1], G[3][k1]);
    float2 t3 = csub(G[1][k1], G[3][k1]);
    a[k1] = cadd(t0, t2);
    a[k1 + 4] = cadd(t1, mni(t3));
    a[k1 + 8] = csub(t0, t2);
    a[k1 + 12] = cadd(t1, mpi(t3));
  }
}

// natural-order inverse DFT-16 (unscaled)
__device__ __forceinline__ void ifft16(float2 a[16]) {
  float2 G[4][4];
#pragma unroll
  for (int r = 0; r < 4; ++r) {
    float2 t0 = cadd(a[r], a[r + 8]);
    float2 t1 = csub(a[r], a[r + 8]);
    float2 t2 = cadd(a[r + 4], a[r + 12]);
    float2 t3 = csub(a[r + 4], a[r + 12]);
    G[r][0] = cadd(t0, t2);
    G[r][1] = cadd(t1, mpi(t3));
    G[r][2] = csub(t0, t2);
    G[r][3] = cadd(t1, mni(t3));
  }
  const float2 W1 = make_float2(C1, -S1);
  const float2 W2 = make_float2(RQ, -RQ);
  const float2 W3 = make_float2(S1, -C1);
  const float2 W6 = make_float2(-RQ, -RQ);
  const float2 W9 = make_float2(-C1, S1);
  G[1][1] = cmulj(G[1][1], W1);
  G[1][2] = cmulj(G[1][2], W2);
  G[1][3] = cmulj(G[1][3], W3);
  G[2][1] = cmulj(G[2][1], W2);
  G[2][2] = mpi(G[2][2]);  // conj(w^4) = +i
  G[2][3] = cmulj(G[2][3], W6);
  G[3][1] = cmulj(G[3][1], W3);
  G[3][2] = cmulj(G[3][2], W6);
  G[3][3] = cmulj(G[3][3], W9);
#pragma unroll
  for (int k1 = 0; k1 < 4; ++k1) {
    float2 t0 = cadd(G[0][k1], G[2][k1]);
    float2 t1 = csub(G[0][k1], G[2][k1]);
    float2 t2 = cadd(G[1][k1], G[3][k1]);
    float2 t3 = csub(G[1][k1], G[3][k1]);
    a[k1] = cadd(t0, t2);
    a[k1 + 4] = cadd(t1, mpi(t3));
    a[k1 + 8] = csub(t0, t2);
    a[k1 + 12] = cadd(t1, mni(t3));
  }
}

// a[q] *= b^q (q=1..15), chained powers
__device__ __forceinline__ void twiddle_pow(float2 a[16], float2 b) {
  float2 p = b;
  a[1] = cmul(a[1], p);
#pragma unroll
  for (int q = 2; q < 16; ++q) {
    p = cmul(p, b);
    a[q] = cmul(a[q], p);
  }
}
// a[q] *= conj(b^q)
__device__ __forceinline__ void twiddle_pow_conj(float2 a[16], float2 b) {
  float2 p = b;
  a[1] = cmulj(a[1], p);
#pragma unroll
  for (int q = 2; q < 16; ++q) {
    p = cmul(p, b);
    a[q] = cmulj(a[q], p);
  }
}

// ---------------- kernel 0: twiddle table tw[j] = e^{-2pi i j/N} ----------------
__global__ __launch_bounds__(256) void build_tw(float2* __restrict__ twg) {
  const int j = blockIdx.x * 256 + threadIdx.x;
  if (j < NFFT) {
    double ang = (-2.0 * 3.14159265358979323846) * (double)j / (double)NFFT;
    twg[j] = make_float2((float)cos(ang), (float)sin(ang));
  }
}

// ---------------- kernel 1: C = fwd-chain(c), stored in fused order ----------------
__global__ __launch_bounds__(256) void build_C(const float* __restrict__ r,
                                               const float2* __restrict__ twg,
                                               float2* __restrict__ Cg) {
  __shared__ float2 d[PAD(NFFT - 1) + 1];
  const int t = threadIdx.x;
  const float2 w1 = twg[t];
  const float2 w2 = twg[(t & 15) * 16];
  float2 a[16];
  // F256 (reads c[k] = r[(N-k)&mask] from global; one-shot kernel, scalar ok)
#pragma unroll
  for (int q = 0; q < 16; ++q) {
    const int idx = t + 256 * q;
    a[q] = make_float2(r[(NFFT - idx) & (NFFT - 1)], 0.f);
  }
  fft16(a);
  twiddle_pow(a, w1);
#pragma unroll
  for (int q = 0; q < 16; ++q) d[PAD(t + 256 * q)] = a[q];
  __syncthreads();
  // F16
  const int base16 = (t >> 4) * 256 + (t & 15);
#pragma unroll
  for (int q = 0; q < 16; ++q) a[q] = d[PAD(base16 + 16 * q)];
  fft16(a);
  twiddle_pow(a, w2);
#pragma unroll
  for (int q = 0; q < 16; ++q) d[PAD(base16 + 16 * q)] = a[q];
  __syncthreads();
  // F1 (no twiddle) -> store straight to Cg in the fused stage's layout
  const int base1 = t * 16;
#pragma unroll
  for (int q = 0; q < 16; ++q) a[q] = d[PAD(base1 + q)];
  fft16(a);
#pragma unroll
  for (int q = 0; q < 16; ++q) Cg[base1 + q] = a[q];
}

// ---------------- kernel 2: packed 2-row radix-16 FFT convolution ----------------
__global__ __launch_bounds__(256, 4) void fft_conv4(
    const float* __restrict__ x, const float2* __restrict__ Cg,
    const float2* __restrict__ twg, const float* __restrict__ bias,
    float* __restrict__ y) {
  __shared__ float2 d[PAD(NFFT - 1) + 1];
  const int t = threadIdx.x;
  const size_t r0 = 2 * (size_t)blockIdx.x;
  const float4* x04 = (const float4*)(x + r0 * NFFT);
  const float4* x14 = (const float4*)(x + (r0 + 1) * NFFT);
  const float4* b4 = (const float4*)bias;
  float4* y04 = (float4*)(y + r0 * NFFT);
  float4* y14 = (float4*)(y + (r0 + 1) * NFFT);

  const float2 w1 = twg[t];             // base for F256/I256 (n = t)
  const float2 w2 = twg[(t & 15) * 16]; // base for F16/I16 (n = t&15)

  float2 a[16];

  // ---- load: float4 from global -> packed complex in LDS ----
#pragma unroll
  for (int w = 0; w < 4; ++w) {
    const int i4 = t + 256 * w;
    const float4 v0 = x04[i4];
    const float4 v1 = x14[i4];
    const int i0 = i4 * 4;
    d[PAD(i0 + 0)] = make_float2(v0.x, v1.x);
    d[PAD(i0 + 1)] = make_float2(v0.y, v1.y);
    d[PAD(i0 + 2)] = make_float2(v0.z, v1.z);
    d[PAD(i0 + 3)] = make_float2(v0.w, v1.w);
  }
  __syncthreads();

  // ---- F256: LDS strided -> fft16 -> twiddle -> LDS ----
#pragma unroll
  for (int q = 0; q < 16; ++q) a[q] = d[PAD(t + 256 * q)];
  fft16(a);
  twiddle_pow(a, w1);
#pragma unroll
  for (int q = 0; q < 16; ++q) d[PAD(t + 256 * q)] = a[q];
  __syncthreads();

  // ---- F16 ----
  const int base16 = (t >> 4) * 256 + (t & 15);
#pragma unroll
  for (int q = 0; q < 16; ++q) a[q] = d[PAD(base16 + 16 * q)];
  fft16(a);
  twiddle_pow(a, w2);
#pragma unroll
  for (int q = 0; q < 16; ++q) d[PAD(base16 + 16 * q)] = a[q];
  __syncthreads();

  // ---- fused F1 + pointwise(C) + I1 (all in registers) ----
  const int base1 = t * 16;
#pragma unroll
  for (int q = 0; q < 16; ++q) a[q] = d[PAD(base1 + q)];
  fft16(a);
  {
    const float4* c4 = (const float4*)(Cg + base1);  // 128 B contiguous/lane
#pragma unroll
    for (int q = 0; q < 8; ++q) {
      const float4 cc = c4[q];
      a[2 * q] = cmul(a[2 * q], make_float2(cc.x, cc.y));
      a[2 * q + 1] = cmul(a[2 * q + 1], make_float2(cc.z, cc.w));
    }
  }
  ifft16(a);
#pragma unroll
  for (int q = 0; q < 16; ++q) d[PAD(base1 + q)] = a[q];
  __syncthreads();

  // ---- I16: un-twiddle then inverse butterfly ----
#pragma unroll
  for (int q = 0; q < 16; ++q) a[q] = d[PAD(base16 + 16 * q)];
  twiddle_pow_conj(a, w2);
  ifft16(a);
#pragma unroll
  for (int q = 0; q < 16; ++q) d[PAD(base16 + 16 * q)] = a[q];
  __syncthreads();

  // ---- I256: strided -> un-twiddle -> ifft16 -> LDS (natural order) ----
#pragma unroll
  for (int q = 0; q < 16; ++q) a[q] = d[PAD(t + 256 * q)];
  twiddle_pow_conj(a, w1);
  ifft16(a);
#pragma unroll
  for (int q = 0; q < 16; ++q) d[PAD(t + 256 * q)] = a[q];
  __syncthreads();

  // ---- store: LDS -> float4 to global (Re -> row0, Im -> row1) ----
  const float s = 1.0f / (float)NFFT;
#pragma unroll
  for (int w = 0; w < 4; ++w) {
    const int i4 = t + 256 * w;
    const int i0 = i4 * 4;
    const float4 bv = b4[i4];
    const float2 d0 = d[PAD(i0 + 0)];
    const float2 d1 = d[PAD(i0 + 1)];
    const float2 d2 = d[PAD(i0 + 2)];
    const float2 d3 = d[PAD(i0 + 3)];
    float4 o0, o1;
    o0.x = d0.x * s + bv.x; o1.x = d0.y * s + bv.x;
    o0.y = d1.x * s + bv.y; o1.y = d1.y * s + bv.y;
    o0.z = d2.x * s + bv.z; o1.z = d2.y * s + bv.z;
    o0.w = d3.x * s + bv.w; o1.w = d3.y * s + bv.w;
    y04[i4] = o0;
    y14[i4] = o1;
  }
}

// ---------------- fallback GEMM (no ws / odd shapes) ----------------

typedef __attribute__((ext_vector_type(8))) short bf16x8;

__device__ __forceinline__ unsigned short f2bf(float f) {
  union { __hip_bfloat16 h; unsigned short u; } v;
  v.h = __float2bfloat16(f);
  return v.u;
}

#define LDP 72

__global__ __launch_bounds__(256) void circ_gemm_fb(
    const float* __restrict__ x, const float* __restrict__ r,
    const float* __restrict__ bias, float* __restrict__ y, int n) {
  __shared__ unsigned short Asf[128][LDP];
  __shared__ unsigned short Bsf[128][LDP];

  const int tid = threadIdx.x;
  const int wid = tid >> 6;
  const int lane = tid & 63;
  const int bm0 = blockIdx.y * 128;
  const int bn0 = blockIdx.x * 128;
  const int m0w = (wid >> 1) * 64;
  const int n0w = (wid & 1) * 64;
  const int lr = lane & 15;
  const int lk = (lane >> 4) * 8;
  const int mask = n - 1;

  f32x4 acc[4][4];
#pragma unroll
  for (int i = 0; i < 4; ++i)
#pragma unroll
    for (int j = 0; j < 4; ++j) acc[i][j] = (f32x4){0.f, 0.f, 0.f, 0.f};

  const int arow = tid >> 4;
  const int acol = (tid & 15) * 4;
  const int bnn = tid >> 1;
  const int bk0 = (tid & 1) * 32;

  for (int k0 = 0; k0 < n; k0 += 64) {
#pragma unroll
    for (int p = 0; p < 8; ++p) {
      const float4 v =
          *(const float4*)&x[(size_t)(bm0 + arow + p * 16) * n + k0 + acol];
      us4 hh;
      hh.x = f2bf(v.x); hh.y = f2bf(v.y); hh.z = f2bf(v.z); hh.w = f2bf(v.w);
      *(us4*)&Asf[arow + p * 16][acol] = hh;
    }
    {
      const int base = k0 + bk0 - bn0 - bnn;
#pragma unroll
      for (int kq = 0; kq < 32; kq += 4) {
        us4 hh;
        hh.x = f2bf(r[(base + kq + 0) & mask]);
        hh.y = f2bf(r[(base + kq + 1) & mask]);
        hh.z = f2bf(r[(base + kq + 2) & mask]);
        hh.w = f2bf(r[(base + kq + 3) & mask]);
        *(us4*)&Bsf[bnn][bk0 + kq] = hh;
      }
    }
    __syncthreads();

#pragma unroll
    for (int kk = 0; kk < 2; ++kk) {
      bf16x8 af[4], bfr[4];
#pragma unroll
      for (int mi = 0; mi < 4; ++mi)
        af[mi] = *(const bf16x8*)&Asf[m0w + mi * 16 + lr][kk * 32 + lk];
#pragma unroll
      for (int ni = 0; ni < 4; ++ni)
        bfr[ni] = *(const bf16x8*)&Bsf[n0w + ni * 16 + lr][kk * 32 + lk];
#pragma unroll
      for (int mi = 0; mi < 4; ++mi)
#pragma unroll
        for (int ni = 0; ni < 4; ++ni)
          acc[mi][ni] = __builtin_amdgcn_mfma_f32_16x16x32_bf16(
              af[mi], bfr[ni], acc[mi][ni], 0, 0, 0);
    }
    __syncthreads();
  }

#pragma unroll
  for (int ni = 0; ni < 4; ++ni) {
    const int col = bn0 + n0w + ni * 16 + lr;
    const float bv = bias[col];
#pragma unroll
    for (int mi = 0; mi < 4; ++mi) {
      const int row0 = bm0 + m0w + mi * 16 + (lane >> 4) * 4;
#pragma unroll
      for (int j = 0; j < 4; ++j)
        y[(size_t)(row0 + j) * n + col] = acc[mi][ni][j] + bv;
    }
  }
}

// ---------------- launch ----------------

extern "C" void kernel_launch(void* const* d_in, const int* in_sizes, int n_in,
                              void* d_out, int out_size, void* d_ws,
                              size_t ws_size, hipStream_t stream) {
  const float* x = (const float*)d_in[0];
  const float* r = (const float*)d_in[1];
  const float* b = (const float*)d_in[2];
  float* y = (float*)d_out;
  const int n = in_sizes[1];          // 4096
  const int batch = in_sizes[0] / n;  // 8192

  if (n == NFFT && (batch & 1) == 0 && ws_size >= 2 * NFFT * sizeof(float2)) {
    float2* twg = (float2*)d_ws;
    float2* Cg = twg + NFFT;
    build_tw<<<NFFT / 256, 256, 0, stream>>>(twg);
    build_C<<<1, 256, 0, stream>>>(r, twg, Cg);
    fft_conv4<<<batch / 2, 256, 0, stream>>>(x, Cg, twg, b, y);
  } else {
    dim3 grid(n / 128, batch / 128);
    circ_gemm_fb<<<grid, 256, 0, stream>>>(x, r, b, y, n);
  }
}

// Round 11
// 86.876 us; speedup vs baseline: 3.0364x; 3.0364x over previous
//
#include <hip/hip_runtime.h>
#include <hip/hip_bf16.h>
#include <math.h>

// y[b,i] = sum_j x[b,j] * r[(j-i) mod N] + bias[i]
//        = circular conv: y = IFFT(FFT(x) * FFT(c)) + bias, c[k] = r[(-k) mod N]
// Radix-8 FFT (N=4096 = 8^4), fp32, in-LDS, two rows packed per FFT.
//   - R8-proven skeleton & I/O (float4 passes through LDS)
//   - twiddles: ONE base load + chained cmul powers (no scattered gathers)
//   - fused middle: fwd<1> + pointwise(CgT q-major, coalesced) + inv<1> in regs
//   - PAD(i)=i+(i>>4)

#define NFFT 4096
#define PAD(i) ((i) + ((i) >> 4))

typedef __attribute__((ext_vector_type(4))) float f32x4;
typedef __attribute__((ext_vector_type(4))) unsigned short us4;

__device__ __forceinline__ float2 cadd(float2 a, float2 b) {
  return make_float2(a.x + b.x, a.y + b.y);
}
__device__ __forceinline__ float2 csub(float2 a, float2 b) {
  return make_float2(a.x - b.x, a.y - b.y);
}
__device__ __forceinline__ float2 cmul(float2 a, float2 b) {
  return make_float2(a.x * b.x - a.y * b.y, a.x * b.y + a.y * b.x);
}
__device__ __forceinline__ float2 cmulj(float2 a, float2 b) {  // a * conj(b)
  return make_float2(a.x * b.x + a.y * b.y, a.y * b.x - a.x * b.y);
}
__device__ __forceinline__ float2 mni(float2 a) {  // a * (-i)
  return make_float2(a.y, -a.x);
}
__device__ __forceinline__ float2 mpi(float2 a) {  // a * (+i)
  return make_float2(-a.y, a.x);
}

// forward 8-point DFT, natural order (verified R7/R8)
__device__ __forceinline__ void fft8(float2 a[8]) {
  float2 es0 = cadd(a[0], a[4]), ed0 = csub(a[0], a[4]);
  float2 es1 = cadd(a[2], a[6]), ed1 = csub(a[2], a[6]);
  float2 E0 = cadd(es0, es1), E2 = csub(es0, es1);
  float2 E1 = cadd(ed0, mni(ed1)), E3 = cadd(ed0, mpi(ed1));
  float2 os0 = cadd(a[1], a[5]), od0 = csub(a[1], a[5]);
  float2 os1 = cadd(a[3], a[7]), od1 = csub(a[3], a[7]);
  float2 O0 = cadd(os0, os1), O2 = csub(os0, os1);
  float2 O1 = cadd(od0, mni(od1)), O3 = cadd(od0, mpi(od1));
  const float c = 0.70710678118654752f;
  O1 = make_float2(c * (O1.x + O1.y), c * (O1.y - O1.x));  // * c(1-i)
  O2 = mni(O2);                                            // * -i
  O3 = make_float2(c * (O3.y - O3.x), -c * (O3.x + O3.y)); // * c(-1-i)
  a[0] = cadd(E0, O0); a[4] = csub(E0, O0);
  a[1] = cadd(E1, O1); a[5] = csub(E1, O1);
  a[2] = cadd(E2, O2); a[6] = csub(E2, O2);
  a[3] = cadd(E3, O3); a[7] = csub(E3, O3);
}

// inverse 8-point DFT, natural order, unscaled (verified R7/R8)
__device__ __forceinline__ void ifft8(float2 z[8]) {
  float2 es0 = cadd(z[0], z[4]), ed0 = csub(z[0], z[4]);
  float2 es1 = cadd(z[2], z[6]), ed1 = csub(z[2], z[6]);
  float2 E0 = cadd(es0, es1), E2 = csub(es0, es1);
  float2 E1 = cadd(ed0, mpi(ed1)), E3 = cadd(ed0, mni(ed1));
  float2 os0 = cadd(z[1], z[5]), od0 = csub(z[1], z[5]);
  float2 os1 = cadd(z[3], z[7]), od1 = csub(z[3], z[7]);
  float2 O0 = cadd(os0, os1), O2 = csub(os0, os1);
  float2 O1 = cadd(od0, mpi(od1)), O3 = cadd(od0, mni(od1));
  const float c = 0.70710678118654752f;
  O1 = make_float2(c * (O1.x - O1.y), c * (O1.x + O1.y));   // * c(1+i)
  O2 = mpi(O2);                                             // * +i
  O3 = make_float2(-c * (O3.x + O3.y), c * (O3.x - O3.y));  // * c(-1+i)
  z[0] = cadd(E0, O0); z[4] = csub(E0, O0);
  z[1] = cadd(E1, O1); z[5] = csub(E1, O1);
  z[2] = cadd(E2, O2); z[6] = csub(E2, O2);
  z[3] = cadd(E3, O3); z[7] = csub(E3, O3);
}

// ---- forward DIF radix-8 stage, chained twiddle powers (1 load / butterfly) ----
template <int M>
__device__ __forceinline__ void fwd_stage8(float2* d,
                                           const float2* __restrict__ twg,
                                           int tid) {
  constexpr int STEP = NFFT / (8 * M);
#pragma unroll
  for (int v = 0; v < 2; ++v) {
    const int u = tid + 256 * v;
    const int n = u & (M - 1);
    const int base = ((u & ~(M - 1)) << 3) + n;
    float2 a[8];
#pragma unroll
    for (int q = 0; q < 8; ++q) a[q] = d[PAD(base + q * M)];
    fft8(a);
    const float2 b = twg[n * STEP];  // M=512: twg[u] coalesced
    float2 p = b;
    d[PAD(base)] = a[0];
    d[PAD(base + M)] = cmul(a[1], p);
#pragma unroll
    for (int q = 2; q < 8; ++q) {
      p = cmul(p, b);
      d[PAD(base + q * M)] = cmul(a[q], p);
    }
  }
}

// ---- inverse DIT radix-8 stage (exact inverse, conj chained powers) ----
template <int M>
__device__ __forceinline__ void inv_stage8(float2* d,
                                           const float2* __restrict__ twg,
                                           int tid) {
  constexpr int STEP = NFFT / (8 * M);
#pragma unroll
  for (int v = 0; v < 2; ++v) {
    const int u = tid + 256 * v;
    const int n = u & (M - 1);
    const int base = ((u & ~(M - 1)) << 3) + n;
    float2 z[8];
    z[0] = d[PAD(base)];
    const float2 b = twg[n * STEP];
    float2 p = b;
    z[1] = cmulj(d[PAD(base + M)], p);
#pragma unroll
    for (int q = 2; q < 8; ++q) {
      p = cmul(p, b);
      z[q] = cmulj(d[PAD(base + q * M)], p);
    }
    ifft8(z);
#pragma unroll
    for (int q = 0; q < 8; ++q) d[PAD(base + q * M)] = z[q];
  }
}

// ---------------- kernel 0: twiddle table tw[j] = e^{-2pi i j/N} ----------------
__global__ __launch_bounds__(256) void build_tw(float2* __restrict__ twg) {
  const int j = blockIdx.x * 256 + threadIdx.x;
  if (j < NFFT) {
    double ang = (-2.0 * 3.14159265358979323846) * (double)j / (double)NFFT;
    twg[j] = make_float2((float)cos(ang), (float)sin(ang));
  }
}

// ------- kernel 1: CgT[q*512+u] = (full fwd chain of c)[8u+q], q-major -------
__global__ __launch_bounds__(256) void build_C(const float* __restrict__ r,
                                               const float2* __restrict__ twg,
                                               float2* __restrict__ CgT) {
  __shared__ float2 d[PAD(NFFT - 1) + 1];
  const int t = threadIdx.x;
  for (int i = t; i < NFFT; i += 256)
    d[PAD(i)] = make_float2(r[(NFFT - i) & (NFFT - 1)], 0.f);
  __syncthreads();
  fwd_stage8<512>(d, twg, t); __syncthreads();
  fwd_stage8<64>(d, twg, t);  __syncthreads();
  fwd_stage8<8>(d, twg, t);   __syncthreads();
  // final fwd<1> per butterfly, store q-major
#pragma unroll
  for (int v = 0; v < 2; ++v) {
    const int u = t + 256 * v;
    float2 a[8];
#pragma unroll
    for (int q = 0; q < 8; ++q) a[q] = d[PAD(8 * u + q)];
    fft8(a);
#pragma unroll
    for (int q = 0; q < 8; ++q) CgT[q * 512 + u] = a[q];
  }
}

// ---------------- kernel 2: packed 2-row radix-8 FFT convolution ----------------
__global__ __launch_bounds__(256, 4) void fft_conv5(
    const float* __restrict__ x, const float2* __restrict__ CgT,
    const float2* __restrict__ twg, const float* __restrict__ bias,
    float* __restrict__ y) {
  __shared__ float2 d[PAD(NFFT - 1) + 1];
  const int t = threadIdx.x;
  const size_t r0 = 2 * (size_t)blockIdx.x;
  const float4* x04 = (const float4*)(x + r0 * NFFT);
  const float4* x14 = (const float4*)(x + (r0 + 1) * NFFT);
  const float4* b4 = (const float4*)bias;
  float4* y04 = (float4*)(y + r0 * NFFT);
  float4* y14 = (float4*)(y + (r0 + 1) * NFFT);

  // ---- load: float4 from global -> packed complex in LDS ----
#pragma unroll
  for (int w = 0; w < 4; ++w) {
    const int i4 = t + 256 * w;
    const float4 v0 = x04[i4];
    const float4 v1 = x14[i4];
    const int i0 = i4 * 4;
    d[PAD(i0 + 0)] = make_float2(v0.x, v1.x);
    d[PAD(i0 + 1)] = make_float2(v0.y, v1.y);
    d[PAD(i0 + 2)] = make_float2(v0.z, v1.z);
    d[PAD(i0 + 3)] = make_float2(v0.w, v1.w);
  }
  __syncthreads();

  // ---- forward DIF ----
  fwd_stage8<512>(d, twg, t); __syncthreads();
  fwd_stage8<64>(d, twg, t);  __syncthreads();
  fwd_stage8<8>(d, twg, t);   __syncthreads();

  // ---- fused fwd<1> + pointwise(CgT) + inv<1>, all in registers ----
#pragma unroll
  for (int v = 0; v < 2; ++v) {
    const int u = t + 256 * v;
    float2 a[8];
#pragma unroll
    for (int q = 0; q < 8; ++q) a[q] = d[PAD(8 * u + q)];
    fft8(a);
#pragma unroll
    for (int q = 0; q < 8; ++q) a[q] = cmul(a[q], CgT[q * 512 + u]);
    ifft8(a);
#pragma unroll
    for (int q = 0; q < 8; ++q) d[PAD(8 * u + q)] = a[q];
  }
  __syncthreads();

  // ---- inverse DIT ----
  inv_stage8<8>(d, twg, t);   __syncthreads();
  inv_stage8<64>(d, twg, t);  __syncthreads();
  inv_stage8<512>(d, twg, t); __syncthreads();

  // ---- store: LDS -> float4 to global (Re -> row0, Im -> row1) ----
  const float s = 1.0f / (float)NFFT;
#pragma unroll
  for (int w = 0; w < 4; ++w) {
    const int i4 = t + 256 * w;
    const int i0 = i4 * 4;
    const float4 bv = b4[i4];
    const float2 d0 = d[PAD(i0 + 0)];
    const float2 d1 = d[PAD(i0 + 1)];
    const float2 d2 = d[PAD(i0 + 2)];
    const float2 d3 = d[PAD(i0 + 3)];
    float4 o0, o1;
    o0.x = d0.x * s + bv.x; o1.x = d0.y * s + bv.x;
    o0.y = d1.x * s + bv.y; o1.y = d1.y * s + bv.y;
    o0.z = d2.x * s + bv.z; o1.z = d2.y * s + bv.z;
    o0.w = d3.x * s + bv.w; o1.w = d3.y * s + bv.w;
    y04[i4] = o0;
    y14[i4] = o1;
  }
}

// ---------------- fallback GEMM (no ws / odd shapes) ----------------

typedef __attribute__((ext_vector_type(8))) short bf16x8;

__device__ __forceinline__ unsigned short f2bf(float f) {
  union { __hip_bfloat16 h; unsigned short u; } v;
  v.h = __float2bfloat16(f);
  return v.u;
}

#define LDP 72

__global__ __launch_bounds__(256) void circ_gemm_fb(
    const float* __restrict__ x, const float* __restrict__ r,
    const float* __restrict__ bias, float* __restrict__ y, int n) {
  __shared__ unsigned short Asf[128][LDP];
  __shared__ unsigned short Bsf[128][LDP];

  const int tid = threadIdx.x;
  const int wid = tid >> 6;
  const int lane = tid & 63;
  const int bm0 = blockIdx.y * 128;
  const int bn0 = blockIdx.x * 128;
  const int m0w = (wid >> 1) * 64;
  const int n0w = (wid & 1) * 64;
  const int lr = lane & 15;
  const int lk = (lane >> 4) * 8;
  const int mask = n - 1;

  f32x4 acc[4][4];
#pragma unroll
  for (int i = 0; i < 4; ++i)
#pragma unroll
    for (int j = 0; j < 4; ++j) acc[i][j] = (f32x4){0.f, 0.f, 0.f, 0.f};

  const int arow = tid >> 4;
  const int acol = (tid & 15) * 4;
  const int bnn = tid >> 1;
  const int bk0 = (tid & 1) * 32;

  for (int k0 = 0; k0 < n; k0 += 64) {
#pragma unroll
    for (int p = 0; p < 8; ++p) {
      const float4 v =
          *(const float4*)&x[(size_t)(bm0 + arow + p * 16) * n + k0 + acol];
      us4 hh;
      hh.x = f2bf(v.x); hh.y = f2bf(v.y); hh.z = f2bf(v.z); hh.w = f2bf(v.w);
      *(us4*)&Asf[arow + p * 16][acol] = hh;
    }
    {
      const int base = k0 + bk0 - bn0 - bnn;
#pragma unroll
      for (int kq = 0; kq < 32; kq += 4) {
        us4 hh;
        hh.x = f2bf(r[(base + kq + 0) & mask]);
        hh.y = f2bf(r[(base + kq + 1) & mask]);
        hh.z = f2bf(r[(base + kq + 2) & mask]);
        hh.w = f2bf(r[(base + kq + 3) & mask]);
        *(us4*)&Bsf[bnn][bk0 + kq] = hh;
      }
    }
    __syncthreads();

#pragma unroll
    for (int kk = 0; kk < 2; ++kk) {
      bf16x8 af[4], bfr[4];
#pragma unroll
      for (int mi = 0; mi < 4; ++mi)
        af[mi] = *(const bf16x8*)&Asf[m0w + mi * 16 + lr][kk * 32 + lk];
#pragma unroll
      for (int ni = 0; ni < 4; ++ni)
        bfr[ni] = *(const bf16x8*)&Bsf[n0w + ni * 16 + lr][kk * 32 + lk];
#pragma unroll
      for (int mi = 0; mi < 4; ++mi)
#pragma unroll
        for (int ni = 0; ni < 4; ++ni)
          acc[mi][ni] = __builtin_amdgcn_mfma_f32_16x16x32_bf16(
              af[mi], bfr[ni], acc[mi][ni], 0, 0, 0);
    }
    __syncthreads();
  }

#pragma unroll
  for (int ni = 0; ni < 4; ++ni) {
    const int col = bn0 + n0w + ni * 16 + lr;
    const float bv = bias[col];
#pragma unroll
    for (int mi = 0; mi < 4; ++mi) {
      const int row0 = bm0 + m0w + mi * 16 + (lane >> 4) * 4;
#pragma unroll
      for (int j = 0; j < 4; ++j)
        y[(size_t)(row0 + j) * n + col] = acc[mi][ni][j] + bv;
    }
  }
}

// ---------------- launch ----------------

extern "C" void kernel_launch(void* const* d_in, const int* in_sizes, int n_in,
                              void* d_out, int out_size, void* d_ws,
                              size_t ws_size, hipStream_t stream) {
  const float* x = (const float*)d_in[0];
  const float* r = (const float*)d_in[1];
  const float* b = (const float*)d_in[2];
  float* y = (float*)d_out;
  const int n = in_sizes[1];          // 4096
  const int batch = in_sizes[0] / n;  // 8192

  if (n == NFFT && (batch & 1) == 0 && ws_size >= 2 * NFFT * sizeof(float2)) {
    float2* twg = (float2*)d_ws;
    float2* CgT = twg + NFFT;
    build_tw<<<NFFT / 256, 256, 0, stream>>>(twg);
    build_C<<<1, 256, 0, stream>>>(r, twg, CgT);
    fft_conv5<<<batch / 2, 256, 0, stream>>>(x, CgT, twg, b, y);
  } else {
    dim3 grid(n / 128, batch / 128);
    circ_gemm_fb<<<grid, 256, 0, stream>>>(x, r, b, y, n);
  }
}

// Round 12
// 84.160 us; speedup vs baseline: 3.1345x; 1.0323x over previous
//
#include <hip/hip_runtime.h>
#include <hip/hip_bf16.h>
#include <math.h>

// y[b,i] = sum_j x[b,j] * r[(j-i) mod N] + bias[i]
//        = circular conv: y = IFFT(FFT(x) * FFT(c)) + bias, c[k] = r[(-k) mod N]
// Radix-8 FFT (N=4096 = 8^4), fp32, in-LDS, two rows packed per FFT.
//   - R11-proven skeleton & I/O (float4 passes through LDS)
//   - complex math on ext_vector float2 -> v_pk_*_f32 packed ops (2x VALU)
//   - twiddles: ONE base load + chained cmul powers
//   - fused middle: fwd<1> + pointwise(CgT q-major) + inv<1> in regs
//   - PAD(i)=i+(i>>4)

#define NFFT 4096
#define PAD(i) ((i) + ((i) >> 4))

typedef __attribute__((ext_vector_type(2))) float v2f;
typedef __attribute__((ext_vector_type(4))) float f32x4;
typedef __attribute__((ext_vector_type(4))) unsigned short us4;

__device__ __forceinline__ v2f cmul(v2f a, v2f b) {
  return a.xx * b + (v2f){-a.y, a.y} * b.yx;
}
__device__ __forceinline__ v2f cmulj(v2f a, v2f b) {  // a * conj(b)
  return (v2f){a.x, -a.x} * b + a.yy * b.yx;
}
__device__ __forceinline__ v2f mni(v2f a) {  // a * (-i)
  return (v2f){a.y, -a.x};
}
__device__ __forceinline__ v2f mpi(v2f a) {  // a * (+i)
  return (v2f){-a.y, a.x};
}

#define RQ 0.70710678118654752f

// forward 8-point DFT, natural order (verified R7/R8/R11)
__device__ __forceinline__ void fft8(v2f a[8]) {
  v2f es0 = a[0] + a[4], ed0 = a[0] - a[4];
  v2f es1 = a[2] + a[6], ed1 = a[2] - a[6];
  v2f E0 = es0 + es1, E2 = es0 - es1;
  v2f E1 = ed0 + mni(ed1), E3 = ed0 + mpi(ed1);
  v2f os0 = a[1] + a[5], od0 = a[1] - a[5];
  v2f os1 = a[3] + a[7], od1 = a[3] - a[7];
  v2f O0 = os0 + os1, O2 = os0 - os1;
  v2f O1 = od0 + mni(od1), O3 = od0 + mpi(od1);
  O1 = RQ * (O1 + mni(O1));  // * c(1-i)
  O2 = mni(O2);              // * -i
  O3 = RQ * (mni(O3) - O3);  // * c(-1-i)
  a[0] = E0 + O0; a[4] = E0 - O0;
  a[1] = E1 + O1; a[5] = E1 - O1;
  a[2] = E2 + O2; a[6] = E2 - O2;
  a[3] = E3 + O3; a[7] = E3 - O3;
}

// inverse 8-point DFT, natural order, unscaled (verified R7/R8/R11)
__device__ __forceinline__ void ifft8(v2f z[8]) {
  v2f es0 = z[0] + z[4], ed0 = z[0] - z[4];
  v2f es1 = z[2] + z[6], ed1 = z[2] - z[6];
  v2f E0 = es0 + es1, E2 = es0 - es1;
  v2f E1 = ed0 + mpi(ed1), E3 = ed0 + mni(ed1);
  v2f os0 = z[1] + z[5], od0 = z[1] - z[5];
  v2f os1 = z[3] + z[7], od1 = z[3] - z[7];
  v2f O0 = os0 + os1, O2 = os0 - os1;
  v2f O1 = od0 + mpi(od1), O3 = od0 + mni(od1);
  O1 = RQ * (O1 + mpi(O1));  // * c(1+i)
  O2 = mpi(O2);              // * +i
  O3 = RQ * (mpi(O3) - O3);  // * c(-1+i)
  z[0] = E0 + O0; z[4] = E0 - O0;
  z[1] = E1 + O1; z[5] = E1 - O1;
  z[2] = E2 + O2; z[6] = E2 - O2;
  z[3] = E3 + O3; z[7] = E3 - O3;
}

// ---- forward DIF radix-8 stage, chained twiddle powers (1 load / butterfly) ----
template <int M>
__device__ __forceinline__ void fwd_stage8(v2f* d, const v2f* __restrict__ twg,
                                           int tid) {
  constexpr int STEP = NFFT / (8 * M);
#pragma unroll
  for (int v = 0; v < 2; ++v) {
    const int u = tid + 256 * v;
    const int n = u & (M - 1);
    const int base = ((u & ~(M - 1)) << 3) + n;
    v2f a[8];
#pragma unroll
    for (int q = 0; q < 8; ++q) a[q] = d[PAD(base + q * M)];
    fft8(a);
    const v2f b = twg[n * STEP];
    v2f p = b;
    d[PAD(base)] = a[0];
    d[PAD(base + M)] = cmul(a[1], p);
#pragma unroll
    for (int q = 2; q < 8; ++q) {
      p = cmul(p, b);
      d[PAD(base + q * M)] = cmul(a[q], p);
    }
  }
}

// ---- inverse DIT radix-8 stage (exact inverse, conj chained powers) ----
template <int M>
__device__ __forceinline__ void inv_stage8(v2f* d, const v2f* __restrict__ twg,
                                           int tid) {
  constexpr int STEP = NFFT / (8 * M);
#pragma unroll
  for (int v = 0; v < 2; ++v) {
    const int u = tid + 256 * v;
    const int n = u & (M - 1);
    const int base = ((u & ~(M - 1)) << 3) + n;
    v2f z[8];
    z[0] = d[PAD(base)];
    const v2f b = twg[n * STEP];
    v2f p = b;
    z[1] = cmulj(d[PAD(base + M)], p);
#pragma unroll
    for (int q = 2; q < 8; ++q) {
      p = cmul(p, b);
      z[q] = cmulj(d[PAD(base + q * M)], p);
    }
    ifft8(z);
#pragma unroll
    for (int q = 0; q < 8; ++q) d[PAD(base + q * M)] = z[q];
  }
}

// ---------------- kernel 0: twiddle table tw[j] = e^{-2pi i j/N} ----------------
__global__ __launch_bounds__(256) void build_tw(v2f* __restrict__ twg) {
  const int j = blockIdx.x * 256 + threadIdx.x;
  if (j < NFFT) {
    double ang = (-2.0 * 3.14159265358979323846) * (double)j / (double)NFFT;
    twg[j] = (v2f){(float)cos(ang), (float)sin(ang)};
  }
}

// ------- kernel 1: CgT[q*512+u] = (full fwd chain of c)[8u+q], q-major -------
__global__ __launch_bounds__(256) void build_C(const float* __restrict__ r,
                                               const v2f* __restrict__ twg,
                                               v2f* __restrict__ CgT) {
  __shared__ v2f d[PAD(NFFT - 1) + 1];
  const int t = threadIdx.x;
  for (int i = t; i < NFFT; i += 256)
    d[PAD(i)] = (v2f){r[(NFFT - i) & (NFFT - 1)], 0.f};
  __syncthreads();
  fwd_stage8<512>(d, twg, t); __syncthreads();
  fwd_stage8<64>(d, twg, t);  __syncthreads();
  fwd_stage8<8>(d, twg, t);   __syncthreads();
#pragma unroll
  for (int v = 0; v < 2; ++v) {
    const int u = t + 256 * v;
    v2f a[8];
#pragma unroll
    for (int q = 0; q < 8; ++q) a[q] = d[PAD(8 * u + q)];
    fft8(a);
#pragma unroll
    for (int q = 0; q < 8; ++q) CgT[q * 512 + u] = a[q];
  }
}

// ---------------- kernel 2: packed 2-row radix-8 FFT convolution ----------------
__global__ __launch_bounds__(256, 4) void fft_conv6(
    const float* __restrict__ x, const v2f* __restrict__ CgT,
    const v2f* __restrict__ twg, const float* __restrict__ bias,
    float* __restrict__ y) {
  __shared__ v2f d[PAD(NFFT - 1) + 1];
  const int t = threadIdx.x;
  const size_t r0 = 2 * (size_t)blockIdx.x;
  const float4* x04 = (const float4*)(x + r0 * NFFT);
  const float4* x14 = (const float4*)(x + (r0 + 1) * NFFT);
  const float4* b4 = (const float4*)bias;
  float4* y04 = (float4*)(y + r0 * NFFT);
  float4* y14 = (float4*)(y + (r0 + 1) * NFFT);

  // ---- load: float4 from global -> packed complex in LDS ----
#pragma unroll
  for (int w = 0; w < 4; ++w) {
    const int i4 = t + 256 * w;
    const float4 v0 = x04[i4];
    const float4 v1 = x14[i4];
    const int i0 = i4 * 4;
    d[PAD(i0 + 0)] = (v2f){v0.x, v1.x};
    d[PAD(i0 + 1)] = (v2f){v0.y, v1.y};
    d[PAD(i0 + 2)] = (v2f){v0.z, v1.z};
    d[PAD(i0 + 3)] = (v2f){v0.w, v1.w};
  }
  __syncthreads();

  // ---- forward DIF ----
  fwd_stage8<512>(d, twg, t); __syncthreads();
  fwd_stage8<64>(d, twg, t);  __syncthreads();
  fwd_stage8<8>(d, twg, t);   __syncthreads();

  // ---- fused fwd<1> + pointwise(CgT) + inv<1>, all in registers ----
#pragma unroll
  for (int v = 0; v < 2; ++v) {
    const int u = t + 256 * v;
    v2f a[8];
#pragma unroll
    for (int q = 0; q < 8; ++q) a[q] = d[PAD(8 * u + q)];
    fft8(a);
#pragma unroll
    for (int q = 0; q < 8; ++q) a[q] = cmul(a[q], CgT[q * 512 + u]);
    ifft8(a);
#pragma unroll
    for (int q = 0; q < 8; ++q) d[PAD(8 * u + q)] = a[q];
  }
  __syncthreads();

  // ---- inverse DIT ----
  inv_stage8<8>(d, twg, t);   __syncthreads();
  inv_stage8<64>(d, twg, t);  __syncthreads();
  inv_stage8<512>(d, twg, t); __syncthreads();

  // ---- store: LDS -> float4 to global (Re -> row0, Im -> row1) ----
  const float s = 1.0f / (float)NFFT;
#pragma unroll
  for (int w = 0; w < 4; ++w) {
    const int i4 = t + 256 * w;
    const int i0 = i4 * 4;
    const float4 bv = b4[i4];
    const v2f d0 = d[PAD(i0 + 0)];
    const v2f d1 = d[PAD(i0 + 1)];
    const v2f d2 = d[PAD(i0 + 2)];
    const v2f d3 = d[PAD(i0 + 3)];
    float4 o0, o1;
    o0.x = d0.x * s + bv.x; o1.x = d0.y * s + bv.x;
    o0.y = d1.x * s + bv.y; o1.y = d1.y * s + bv.y;
    o0.z = d2.x * s + bv.z; o1.z = d2.y * s + bv.z;
    o0.w = d3.x * s + bv.w; o1.w = d3.y * s + bv.w;
    y04[i4] = o0;
    y14[i4] = o1;
  }
}

// ---------------- fallback GEMM (no ws / odd shapes) ----------------

typedef __attribute__((ext_vector_type(8))) short bf16x8;

__device__ __forceinline__ unsigned short f2bf(float f) {
  union { __hip_bfloat16 h; unsigned short u; } v;
  v.h = __float2bfloat16(f);
  return v.u;
}

#define LDP 72

__global__ __launch_bounds__(256) void circ_gemm_fb(
    const float* __restrict__ x, const float* __restrict__ r,
    const float* __restrict__ bias, float* __restrict__ y, int n) {
  __shared__ unsigned short Asf[128][LDP];
  __shared__ unsigned short Bsf[128][LDP];

  const int tid = threadIdx.x;
  const int wid = tid >> 6;
  const int lane = tid & 63;
  const int bm0 = blockIdx.y * 128;
  const int bn0 = blockIdx.x * 128;
  const int m0w = (wid >> 1) * 64;
  const int n0w = (wid & 1) * 64;
  const int lr = lane & 15;
  const int lk = (lane >> 4) * 8;
  const int mask = n - 1;

  f32x4 acc[4][4];
#pragma unroll
  for (int i = 0; i < 4; ++i)
#pragma unroll
    for (int j = 0; j < 4; ++j) acc[i][j] = (f32x4){0.f, 0.f, 0.f, 0.f};

  const int arow = tid >> 4;
  const int acol = (tid & 15) * 4;
  const int bnn = tid >> 1;
  const int bk0 = (tid & 1) * 32;

  for (int k0 = 0; k0 < n; k0 += 64) {
#pragma unroll
    for (int p = 0; p < 8; ++p) {
      const float4 v =
          *(const float4*)&x[(size_t)(bm0 + arow + p * 16) * n + k0 + acol];
      us4 hh;
      hh.x = f2bf(v.x); hh.y = f2bf(v.y); hh.z = f2bf(v.z); hh.w = f2bf(v.w);
      *(us4*)&Asf[arow + p * 16][acol] = hh;
    }
    {
      const int base = k0 + bk0 - bn0 - bnn;
#pragma unroll
      for (int kq = 0; kq < 32; kq += 4) {
        us4 hh;
        hh.x = f2bf(r[(base + kq + 0) & mask]);
        hh.y = f2bf(r[(base + kq + 1) & mask]);
        hh.z = f2bf(r[(base + kq + 2) & mask]);
        hh.w = f2bf(r[(base + kq + 3) & mask]);
        *(us4*)&Bsf[bnn][bk0 + kq] = hh;
      }
    }
    __syncthreads();

#pragma unroll
    for (int kk = 0; kk < 2; ++kk) {
      bf16x8 af[4], bfr[4];
#pragma unroll
      for (int mi = 0; mi < 4; ++mi)
        af[mi] = *(const bf16x8*)&Asf[m0w + mi * 16 + lr][kk * 32 + lk];
#pragma unroll
      for (int ni = 0; ni < 4; ++ni)
        bfr[ni] = *(const bf16x8*)&Bsf[n0w + ni * 16 + lr][kk * 32 + lk];
#pragma unroll
      for (int mi = 0; mi < 4; ++mi)
#pragma unroll
        for (int ni = 0; ni < 4; ++ni)
          acc[mi][ni] = __builtin_amdgcn_mfma_f32_16x16x32_bf16(
              af[mi], bfr[ni], acc[mi][ni], 0, 0, 0);
    }
    __syncthreads();
  }

#pragma unroll
  for (int ni = 0; ni < 4; ++ni) {
    const int col = bn0 + n0w + ni * 16 + lr;
    const float bv = bias[col];
#pragma unroll
    for (int mi = 0; mi < 4; ++mi) {
      const int row0 = bm0 + m0w + mi * 16 + (lane >> 4) * 4;
#pragma unroll
      for (int j = 0; j < 4; ++j)
        y[(size_t)(row0 + j) * n + col] = acc[mi][ni][j] + bv;
    }
  }
}

// ---------------- launch ----------------

extern "C" void kernel_launch(void* const* d_in, const int* in_sizes, int n_in,
                              void* d_out, int out_size, void* d_ws,
                              size_t ws_size, hipStream_t stream) {
  const float* x = (const float*)d_in[0];
  const float* r = (const float*)d_in[1];
  const float* b = (const float*)d_in[2];
  float* y = (float*)d_out;
  const int n = in_sizes[1];          // 4096
  const int batch = in_sizes[0] / n;  // 8192

  if (n == NFFT && (batch & 1) == 0 && ws_size >= 2 * NFFT * sizeof(v2f)) {
    v2f* twg = (v2f*)d_ws;
    v2f* CgT = twg + NFFT;
    build_tw<<<NFFT / 256, 256, 0, stream>>>(twg);
    build_C<<<1, 256, 0, stream>>>(r, twg, CgT);
    fft_conv6<<<batch / 2, 256, 0, stream>>>(x, CgT, twg, b, y);
  } else {
    dim3 grid(n / 128, batch / 128);
    circ_gemm_fb<<<grid, 256, 0, stream>>>(x, r, b, y, n);
  }
}

// Round 13
// 82.697 us; speedup vs baseline: 3.1899x; 1.0177x over previous
//
#include <hip/hip_runtime.h>
#include <hip/hip_bf16.h>
#include <math.h>

// y[b,i] = sum_j x[b,j] * r[(j-i) mod N] + bias[i]
//        = circular conv: y = IFFT(FFT(x) * FFT(c)) + bias, c[k] = r[(-k) mod N]
// Radix-8 FFT (N=4096 = 8^4), fp32, in-LDS, two rows packed per FFT.
//   - 512 threads/block, ONE butterfly/thread/stage -> 32 waves/CU (100% occ)
//   - twiddles: ONE base load + TREE powers (dep chain 6 -> 3)
//   - fused middle: fwd<1> + pointwise(CgT q-major) + inv<1> in regs
//   - float4 global I/O through LDS; PAD(i)=i+(i>>4)

#define NFFT 4096
#define PAD(i) ((i) + ((i) >> 4))

typedef __attribute__((ext_vector_type(2))) float v2f;
typedef __attribute__((ext_vector_type(4))) float f32x4;
typedef __attribute__((ext_vector_type(4))) unsigned short us4;

__device__ __forceinline__ v2f cmul(v2f a, v2f b) {
  return a.xx * b + (v2f){-a.y, a.y} * b.yx;
}
__device__ __forceinline__ v2f cmulj(v2f a, v2f b) {  // a * conj(b)
  return (v2f){a.x, -a.x} * b + a.yy * b.yx;
}
__device__ __forceinline__ v2f mni(v2f a) {  // a * (-i)
  return (v2f){a.y, -a.x};
}
__device__ __forceinline__ v2f mpi(v2f a) {  // a * (+i)
  return (v2f){-a.y, a.x};
}

#define RQ 0.70710678118654752f

// forward 8-point DFT, natural order (verified R7..R12)
__device__ __forceinline__ void fft8(v2f a[8]) {
  v2f es0 = a[0] + a[4], ed0 = a[0] - a[4];
  v2f es1 = a[2] + a[6], ed1 = a[2] - a[6];
  v2f E0 = es0 + es1, E2 = es0 - es1;
  v2f E1 = ed0 + mni(ed1), E3 = ed0 + mpi(ed1);
  v2f os0 = a[1] + a[5], od0 = a[1] - a[5];
  v2f os1 = a[3] + a[7], od1 = a[3] - a[7];
  v2f O0 = os0 + os1, O2 = os0 - os1;
  v2f O1 = od0 + mni(od1), O3 = od0 + mpi(od1);
  O1 = RQ * (O1 + mni(O1));  // * c(1-i)
  O2 = mni(O2);              // * -i
  O3 = RQ * (mni(O3) - O3);  // * c(-1-i)
  a[0] = E0 + O0; a[4] = E0 - O0;
  a[1] = E1 + O1; a[5] = E1 - O1;
  a[2] = E2 + O2; a[6] = E2 - O2;
  a[3] = E3 + O3; a[7] = E3 - O3;
}

// inverse 8-point DFT, natural order, unscaled (verified R7..R12)
__device__ __forceinline__ void ifft8(v2f z[8]) {
  v2f es0 = z[0] + z[4], ed0 = z[0] - z[4];
  v2f es1 = z[2] + z[6], ed1 = z[2] - z[6];
  v2f E0 = es0 + es1, E2 = es0 - es1;
  v2f E1 = ed0 + mpi(ed1), E3 = ed0 + mni(ed1);
  v2f os0 = z[1] + z[5], od0 = z[1] - z[5];
  v2f os1 = z[3] + z[7], od1 = z[3] - z[7];
  v2f O0 = os0 + os1, O2 = os0 - os1;
  v2f O1 = od0 + mpi(od1), O3 = od0 + mni(od1);
  O1 = RQ * (O1 + mpi(O1));  // * c(1+i)
  O2 = mpi(O2);              // * +i
  O3 = RQ * (mpi(O3) - O3);  // * c(-1+i)
  z[0] = E0 + O0; z[4] = E0 - O0;
  z[1] = E1 + O1; z[5] = E1 - O1;
  z[2] = E2 + O2; z[6] = E2 - O2;
  z[3] = E3 + O3; z[7] = E3 - O3;
}

// ---- forward DIF radix-8 stage: ONE butterfly (index u) ----
template <int M>
__device__ __forceinline__ void fwd_stage8(v2f* d, const v2f* __restrict__ twg,
                                           int u) {
  constexpr int STEP = NFFT / (8 * M);
  const int n = u & (M - 1);
  const int base = ((u & ~(M - 1)) << 3) + n;
  v2f a[8];
#pragma unroll
  for (int q = 0; q < 8; ++q) a[q] = d[PAD(base + q * M)];
  fft8(a);
  const v2f b = twg[n * STEP];
  const v2f p2 = cmul(b, b);
  const v2f p3 = cmul(p2, b);
  const v2f p4 = cmul(p2, p2);
  const v2f p5 = cmul(p3, p2);
  const v2f p6 = cmul(p3, p3);
  const v2f p7 = cmul(p4, p3);
  d[PAD(base)] = a[0];
  d[PAD(base + 1 * M)] = cmul(a[1], b);
  d[PAD(base + 2 * M)] = cmul(a[2], p2);
  d[PAD(base + 3 * M)] = cmul(a[3], p3);
  d[PAD(base + 4 * M)] = cmul(a[4], p4);
  d[PAD(base + 5 * M)] = cmul(a[5], p5);
  d[PAD(base + 6 * M)] = cmul(a[6], p6);
  d[PAD(base + 7 * M)] = cmul(a[7], p7);
}

// ---- inverse DIT radix-8 stage: ONE butterfly (index u) ----
template <int M>
__device__ __forceinline__ void inv_stage8(v2f* d, const v2f* __restrict__ twg,
                                           int u) {
  constexpr int STEP = NFFT / (8 * M);
  const int n = u & (M - 1);
  const int base = ((u & ~(M - 1)) << 3) + n;
  const v2f b = twg[n * STEP];
  const v2f p2 = cmul(b, b);
  const v2f p3 = cmul(p2, b);
  const v2f p4 = cmul(p2, p2);
  const v2f p5 = cmul(p3, p2);
  const v2f p6 = cmul(p3, p3);
  const v2f p7 = cmul(p4, p3);
  v2f z[8];
  z[0] = d[PAD(base)];
  z[1] = cmulj(d[PAD(base + 1 * M)], b);
  z[2] = cmulj(d[PAD(base + 2 * M)], p2);
  z[3] = cmulj(d[PAD(base + 3 * M)], p3);
  z[4] = cmulj(d[PAD(base + 4 * M)], p4);
  z[5] = cmulj(d[PAD(base + 5 * M)], p5);
  z[6] = cmulj(d[PAD(base + 6 * M)], p6);
  z[7] = cmulj(d[PAD(base + 7 * M)], p7);
  ifft8(z);
#pragma unroll
  for (int q = 0; q < 8; ++q) d[PAD(base + q * M)] = z[q];
}

// ---------------- kernel 0: twiddle table tw[j] = e^{-2pi i j/N} ----------------
__global__ __launch_bounds__(256) void build_tw(v2f* __restrict__ twg) {
  const int j = blockIdx.x * 256 + threadIdx.x;
  if (j < NFFT) {
    double ang = (-2.0 * 3.14159265358979323846) * (double)j / (double)NFFT;
    twg[j] = (v2f){(float)cos(ang), (float)sin(ang)};
  }
}

// ------- kernel 1: CgT[q*512+u] = (full fwd chain of c)[8u+q], q-major -------
__global__ __launch_bounds__(256) void build_C(const float* __restrict__ r,
                                               const v2f* __restrict__ twg,
                                               v2f* __restrict__ CgT) {
  __shared__ v2f d[PAD(NFFT - 1) + 1];
  const int t = threadIdx.x;
  for (int i = t; i < NFFT; i += 256)
    d[PAD(i)] = (v2f){r[(NFFT - i) & (NFFT - 1)], 0.f};
  __syncthreads();
  fwd_stage8<512>(d, twg, t); fwd_stage8<512>(d, twg, t + 256); __syncthreads();
  fwd_stage8<64>(d, twg, t);  fwd_stage8<64>(d, twg, t + 256);  __syncthreads();
  fwd_stage8<8>(d, twg, t);   fwd_stage8<8>(d, twg, t + 256);   __syncthreads();
#pragma unroll
  for (int v = 0; v < 2; ++v) {
    const int u = t + 256 * v;
    v2f a[8];
#pragma unroll
    for (int q = 0; q < 8; ++q) a[q] = d[PAD(8 * u + q)];
    fft8(a);
#pragma unroll
    for (int q = 0; q < 8; ++q) CgT[q * 512 + u] = a[q];
  }
}

// -------- kernel 2: packed 2-row radix-8 FFT convolution, 512 threads --------
__global__ __launch_bounds__(512) void fft_conv7(
    const float* __restrict__ x, const v2f* __restrict__ CgT,
    const v2f* __restrict__ twg, const float* __restrict__ bias,
    float* __restrict__ y) {
  __shared__ v2f d[PAD(NFFT - 1) + 1];
  const int t = threadIdx.x;  // 0..511
  const size_t r0 = 2 * (size_t)blockIdx.x;
  const float4* x04 = (const float4*)(x + r0 * NFFT);
  const float4* x14 = (const float4*)(x + (r0 + 1) * NFFT);
  const float4* b4 = (const float4*)bias;
  float4* y04 = (float4*)(y + r0 * NFFT);
  float4* y14 = (float4*)(y + (r0 + 1) * NFFT);

  // ---- load: float4 from global -> packed complex in LDS ----
#pragma unroll
  for (int w = 0; w < 2; ++w) {
    const int i4 = t + 512 * w;
    const float4 v0 = x04[i4];
    const float4 v1 = x14[i4];
    const int i0 = i4 * 4;
    d[PAD(i0 + 0)] = (v2f){v0.x, v1.x};
    d[PAD(i0 + 1)] = (v2f){v0.y, v1.y};
    d[PAD(i0 + 2)] = (v2f){v0.z, v1.z};
    d[PAD(i0 + 3)] = (v2f){v0.w, v1.w};
  }
  __syncthreads();

  // ---- forward DIF (one butterfly per thread) ----
  fwd_stage8<512>(d, twg, t); __syncthreads();
  fwd_stage8<64>(d, twg, t);  __syncthreads();
  fwd_stage8<8>(d, twg, t);   __syncthreads();

  // ---- fused fwd<1> + pointwise(CgT) + inv<1>, all in registers ----
  {
    v2f a[8];
#pragma unroll
    for (int q = 0; q < 8; ++q) a[q] = d[PAD(8 * t + q)];
    fft8(a);
#pragma unroll
    for (int q = 0; q < 8; ++q) a[q] = cmul(a[q], CgT[q * 512 + t]);
    ifft8(a);
#pragma unroll
    for (int q = 0; q < 8; ++q) d[PAD(8 * t + q)] = a[q];
  }
  __syncthreads();

  // ---- inverse DIT ----
  inv_stage8<8>(d, twg, t);   __syncthreads();
  inv_stage8<64>(d, twg, t);  __syncthreads();
  inv_stage8<512>(d, twg, t); __syncthreads();

  // ---- store: LDS -> float4 to global (Re -> row0, Im -> row1) ----
  const float s = 1.0f / (float)NFFT;
#pragma unroll
  for (int w = 0; w < 2; ++w) {
    const int i4 = t + 512 * w;
    const int i0 = i4 * 4;
    const float4 bv = b4[i4];
    const v2f d0 = d[PAD(i0 + 0)];
    const v2f d1 = d[PAD(i0 + 1)];
    const v2f d2 = d[PAD(i0 + 2)];
    const v2f d3 = d[PAD(i0 + 3)];
    float4 o0, o1;
    o0.x = d0.x * s + bv.x; o1.x = d0.y * s + bv.x;
    o0.y = d1.x * s + bv.y; o1.y = d1.y * s + bv.y;
    o0.z = d2.x * s + bv.z; o1.z = d2.y * s + bv.z;
    o0.w = d3.x * s + bv.w; o1.w = d3.y * s + bv.w;
    y04[i4] = o0;
    y14[i4] = o1;
  }
}

// ---------------- fallback GEMM (no ws / odd shapes) ----------------

typedef __attribute__((ext_vector_type(8))) short bf16x8;

__device__ __forceinline__ unsigned short f2bf(float f) {
  union { __hip_bfloat16 h; unsigned short u; } v;
  v.h = __float2bfloat16(f);
  return v.u;
}

#define LDP 72

__global__ __launch_bounds__(256) void circ_gemm_fb(
    const float* __restrict__ x, const float* __restrict__ r,
    const float* __restrict__ bias, float* __restrict__ y, int n) {
  __shared__ unsigned short Asf[128][LDP];
  __shared__ unsigned short Bsf[128][LDP];

  const int tid = threadIdx.x;
  const int wid = tid >> 6;
  const int lane = tid & 63;
  const int bm0 = blockIdx.y * 128;
  const int bn0 = blockIdx.x * 128;
  const int m0w = (wid >> 1) * 64;
  const int n0w = (wid & 1) * 64;
  const int lr = lane & 15;
  const int lk = (lane >> 4) * 8;
  const int mask = n - 1;

  f32x4 acc[4][4];
#pragma unroll
  for (int i = 0; i < 4; ++i)
#pragma unroll
    for (int j = 0; j < 4; ++j) acc[i][j] = (f32x4){0.f, 0.f, 0.f, 0.f};

  const int arow = tid >> 4;
  const int acol = (tid & 15) * 4;
  const int bnn = tid >> 1;
  const int bk0 = (tid & 1) * 32;

  for (int k0 = 0; k0 < n; k0 += 64) {
#pragma unroll
    for (int p = 0; p < 8; ++p) {
      const float4 v =
          *(const float4*)&x[(size_t)(bm0 + arow + p * 16) * n + k0 + acol];
      us4 hh;
      hh.x = f2bf(v.x); hh.y = f2bf(v.y); hh.z = f2bf(v.z); hh.w = f2bf(v.w);
      *(us4*)&Asf[arow + p * 16][acol] = hh;
    }
    {
      const int base = k0 + bk0 - bn0 - bnn;
#pragma unroll
      for (int kq = 0; kq < 32; kq += 4) {
        us4 hh;
        hh.x = f2bf(r[(base + kq + 0) & mask]);
        hh.y = f2bf(r[(base + kq + 1) & mask]);
        hh.z = f2bf(r[(base + kq + 2) & mask]);
        hh.w = f2bf(r[(base + kq + 3) & mask]);
        *(us4*)&Bsf[bnn][bk0 + kq] = hh;
      }
    }
    __syncthreads();

#pragma unroll
    for (int kk = 0; kk < 2; ++kk) {
      bf16x8 af[4], bfr[4];
#pragma unroll
      for (int mi = 0; mi < 4; ++mi)
        af[mi] = *(const bf16x8*)&Asf[m0w + mi * 16 + lr][kk * 32 + lk];
#pragma unroll
      for (int ni = 0; ni < 4; ++ni)
        bfr[ni] = *(const bf16x8*)&Bsf[n0w + ni * 16 + lr][kk * 32 + lk];
#pragma unroll
      for (int mi = 0; mi < 4; ++mi)
#pragma unroll
        for (int ni = 0; ni < 4; ++ni)
          acc[mi][ni] = __builtin_amdgcn_mfma_f32_16x16x32_bf16(
              af[mi], bfr[ni], acc[mi][ni], 0, 0, 0);
    }
    __syncthreads();
  }

#pragma unroll
  for (int ni = 0; ni < 4; ++ni) {
    const int col = bn0 + n0w + ni * 16 + lr;
    const float bv = bias[col];
#pragma unroll
    for (int mi = 0; mi < 4; ++mi) {
      const int row0 = bm0 + m0w + mi * 16 + (lane >> 4) * 4;
#pragma unroll
      for (int j = 0; j < 4; ++j)
        y[(size_t)(row0 + j) * n + col] = acc[mi][ni][j] + bv;
    }
  }
}

// ---------------- launch ----------------

extern "C" void kernel_launch(void* const* d_in, const int* in_sizes, int n_in,
                              void* d_out, int out_size, void* d_ws,
                              size_t ws_size, hipStream_t stream) {
  const float* x = (const float*)d_in[0];
  const float* r = (const float*)d_in[1];
  const float* b = (const float*)d_in[2];
  float* y = (float*)d_out;
  const int n = in_sizes[1];          // 4096
  const int batch = in_sizes[0] / n;  // 8192

  if (n == NFFT && (batch & 1) == 0 && ws_size >= 2 * NFFT * sizeof(v2f)) {
    v2f* twg = (v2f*)d_ws;
    v2f* CgT = twg + NFFT;
    build_tw<<<NFFT / 256, 256, 0, stream>>>(twg);
    build_C<<<1, 256, 0, stream>>>(r, twg, CgT);
    fft_conv7<<<batch / 2, 512, 0, stream>>>(x, CgT, twg, b, y);
  } else {
    dim3 grid(n / 128, batch / 128);
    circ_gemm_fb<<<grid, 256, 0, stream>>>(x, r, b, y, n);
  }
}

// Round 14
// 79.946 us; speedup vs baseline: 3.2997x; 1.0344x over previous
//
#include <hip/hip_runtime.h>
#include <hip/hip_bf16.h>
#include <math.h>

// y[b,i] = sum_j x[b,j] * r[(j-i) mod N] + bias[i]
//        = circular conv: y = IFFT(FFT(x) * FFT(c)) + bias, c[k] = r[(-k) mod N]
// Radix-8 FFT (N=4096 = 8^4), fp32, in-LDS, two rows packed per FFT.
//   - complex math via VOP3P packed fp32 inline asm (v_pk_add/mul/fma_f32
//     with op_sel/neg folding all swizzles) -> ~2x fewer VALU issues
//   - 512 threads/block, one butterfly/thread/stage
//   - twiddles: ONE base load + tree powers (cmul = 2 instrs)
//   - fused middle: fwd<1> + pointwise(CgT q-major) + inv<1> in regs
//   - float4 global I/O through LDS; PAD(i)=i+(i>>4)

#define NFFT 4096
#define PAD(i) ((i) + ((i) >> 4))

typedef __attribute__((ext_vector_type(2))) float v2f;
typedef __attribute__((ext_vector_type(4))) float f32x4;
typedef __attribute__((ext_vector_type(4))) unsigned short us4;

#define RQ 0.70710678118654752f

// ---- VOP3P packed-fp32 primitives ----
__device__ __forceinline__ v2f padd(v2f a, v2f b) {
  v2f r;
  asm("v_pk_add_f32 %0, %1, %2" : "=v"(r) : "v"(a), "v"(b));
  return r;
}
__device__ __forceinline__ v2f psub(v2f a, v2f b) {
  v2f r;
  asm("v_pk_add_f32 %0, %1, %2 neg_lo:[0,1] neg_hi:[0,1]"
      : "=v"(r) : "v"(a), "v"(b));
  return r;
}
__device__ __forceinline__ v2f pmul(v2f a, v2f b) {
  v2f r;
  asm("v_pk_mul_f32 %0, %1, %2" : "=v"(r) : "v"(a), "v"(b));
  return r;
}
// a + (-i)*b = {a.x + b.y, a.y - b.x}
__device__ __forceinline__ v2f addmni(v2f a, v2f b) {
  v2f r;
  asm("v_pk_add_f32 %0, %1, %2 op_sel:[0,1] op_sel_hi:[1,0] neg_hi:[0,1]"
      : "=v"(r) : "v"(a), "v"(b));
  return r;
}
// a + (+i)*b = {a.x - b.y, a.y + b.x}
__device__ __forceinline__ v2f addmpi(v2f a, v2f b) {
  v2f r;
  asm("v_pk_add_f32 %0, %1, %2 op_sel:[0,1] op_sel_hi:[1,0] neg_lo:[0,1]"
      : "=v"(r) : "v"(a), "v"(b));
  return r;
}
// complex a*b: t={ax*bx, ax*by}; r={t.lo - ay*by, t.hi + ay*bx}
__device__ __forceinline__ v2f cmul(v2f a, v2f b) {
  v2f t, r;
  asm("v_pk_mul_f32 %0, %1, %2 op_sel:[0,0] op_sel_hi:[0,1]"
      : "=v"(t) : "v"(a), "v"(b));
  asm("v_pk_fma_f32 %0, %1, %2, %3 op_sel:[1,1,0] op_sel_hi:[1,0,1] neg_lo:[1,0,0]"
      : "=v"(r) : "v"(a), "v"(b), "v"(t));
  return r;
}
// complex a*conj(b): t={ax*bx, ay*bx}; r={t.lo + ay*by, t.hi - ax*by}
__device__ __forceinline__ v2f cmulj(v2f a, v2f b) {
  v2f t, r;
  asm("v_pk_mul_f32 %0, %1, %2 op_sel:[0,0] op_sel_hi:[1,0]"
      : "=v"(t) : "v"(a), "v"(b));
  asm("v_pk_fma_f32 %0, %1, %2, %3 op_sel:[1,1,0] op_sel_hi:[0,1,1] neg_hi:[1,0,0]"
      : "=v"(r) : "v"(a), "v"(b), "v"(t));
  return r;
}

// forward 8-point DFT, natural order (algebra verified R7..R13; pk-folded)
__device__ __forceinline__ void fft8(v2f a[8]) {
  const v2f rq2 = {RQ, RQ};
  v2f es0 = padd(a[0], a[4]), ed0 = psub(a[0], a[4]);
  v2f es1 = padd(a[2], a[6]), ed1 = psub(a[2], a[6]);
  v2f E0 = padd(es0, es1), E2 = psub(es0, es1);
  v2f E1 = addmni(ed0, ed1), E3 = addmpi(ed0, ed1);
  v2f os0 = padd(a[1], a[5]), od0 = psub(a[1], a[5]);
  v2f os1 = padd(a[3], a[7]), od1 = psub(a[3], a[7]);
  v2f O0 = padd(os0, os1), O2 = psub(os0, os1);
  v2f O1 = addmni(od0, od1), O3 = addmpi(od0, od1);
  O1 = pmul(addmni(O1, O1), rq2);         // RQ*(1-i)*O1
  v2f u3 = pmul(addmpi(O3, O3), rq2);     // RQ*(1+i)*O3 ; O3' = -u3
  a[0] = padd(E0, O0); a[4] = psub(E0, O0);
  a[1] = padd(E1, O1); a[5] = psub(E1, O1);
  a[2] = addmni(E2, O2); a[6] = addmpi(E2, O2);  // fold O2*(-i)
  a[3] = psub(E3, u3); a[7] = padd(E3, u3);
}

// inverse 8-point DFT, natural order, unscaled (pk-folded)
__device__ __forceinline__ void ifft8(v2f z[8]) {
  const v2f rq2 = {RQ, RQ};
  v2f es0 = padd(z[0], z[4]), ed0 = psub(z[0], z[4]);
  v2f es1 = padd(z[2], z[6]), ed1 = psub(z[2], z[6]);
  v2f E0 = padd(es0, es1), E2 = psub(es0, es1);
  v2f E1 = addmpi(ed0, ed1), E3 = addmni(ed0, ed1);
  v2f os0 = padd(z[1], z[5]), od0 = psub(z[1], z[5]);
  v2f os1 = padd(z[3], z[7]), od1 = psub(z[3], z[7]);
  v2f O0 = padd(os0, os1), O2 = psub(os0, os1);
  v2f O1 = addmpi(od0, od1), O3 = addmni(od0, od1);
  O1 = pmul(addmpi(O1, O1), rq2);         // RQ*(1+i)*O1
  v2f u3 = pmul(addmni(O3, O3), rq2);     // RQ*(1-i)*O3 ; O3' = -u3
  z[0] = padd(E0, O0); z[4] = psub(E0, O0);
  z[1] = padd(E1, O1); z[5] = psub(E1, O1);
  z[2] = addmpi(E2, O2); z[6] = addmni(E2, O2);  // fold O2*(+i)
  z[3] = psub(E3, u3); z[7] = padd(E3, u3);
}

// ---- forward DIF radix-8 stage: ONE butterfly (index u) ----
template <int M>
__device__ __forceinline__ void fwd_stage8(v2f* d, const v2f* __restrict__ twg,
                                           int u) {
  constexpr int STEP = NFFT / (8 * M);
  const int n = u & (M - 1);
  const int base = ((u & ~(M - 1)) << 3) + n;
  v2f a[8];
#pragma unroll
  for (int q = 0; q < 8; ++q) a[q] = d[PAD(base + q * M)];
  fft8(a);
  const v2f b = twg[n * STEP];
  const v2f p2 = cmul(b, b);
  const v2f p3 = cmul(p2, b);
  const v2f p4 = cmul(p2, p2);
  const v2f p5 = cmul(p3, p2);
  const v2f p6 = cmul(p3, p3);
  const v2f p7 = cmul(p4, p3);
  d[PAD(base)] = a[0];
  d[PAD(base + 1 * M)] = cmul(a[1], b);
  d[PAD(base + 2 * M)] = cmul(a[2], p2);
  d[PAD(base + 3 * M)] = cmul(a[3], p3);
  d[PAD(base + 4 * M)] = cmul(a[4], p4);
  d[PAD(base + 5 * M)] = cmul(a[5], p5);
  d[PAD(base + 6 * M)] = cmul(a[6], p6);
  d[PAD(base + 7 * M)] = cmul(a[7], p7);
}

// ---- inverse DIT radix-8 stage: ONE butterfly (index u) ----
template <int M>
__device__ __forceinline__ void inv_stage8(v2f* d, const v2f* __restrict__ twg,
                                           int u) {
  constexpr int STEP = NFFT / (8 * M);
  const int n = u & (M - 1);
  const int base = ((u & ~(M - 1)) << 3) + n;
  const v2f b = twg[n * STEP];
  const v2f p2 = cmul(b, b);
  const v2f p3 = cmul(p2, b);
  const v2f p4 = cmul(p2, p2);
  const v2f p5 = cmul(p3, p2);
  const v2f p6 = cmul(p3, p3);
  const v2f p7 = cmul(p4, p3);
  v2f z[8];
  z[0] = d[PAD(base)];
  z[1] = cmulj(d[PAD(base + 1 * M)], b);
  z[2] = cmulj(d[PAD(base + 2 * M)], p2);
  z[3] = cmulj(d[PAD(base + 3 * M)], p3);
  z[4] = cmulj(d[PAD(base + 4 * M)], p4);
  z[5] = cmulj(d[PAD(base + 5 * M)], p5);
  z[6] = cmulj(d[PAD(base + 6 * M)], p6);
  z[7] = cmulj(d[PAD(base + 7 * M)], p7);
  ifft8(z);
#pragma unroll
  for (int q = 0; q < 8; ++q) d[PAD(base + q * M)] = z[q];
}

// ---------------- kernel 0: twiddle table tw[j] = e^{-2pi i j/N} ----------------
__global__ __launch_bounds__(256) void build_tw(v2f* __restrict__ twg) {
  const int j = blockIdx.x * 256 + threadIdx.x;
  if (j < NFFT) {
    double ang = (-2.0 * 3.14159265358979323846) * (double)j / (double)NFFT;
    twg[j] = (v2f){(float)cos(ang), (float)sin(ang)};
  }
}

// ------- kernel 1: CgT[q*512+u] = (full fwd chain of c)[8u+q], q-major -------
__global__ __launch_bounds__(256) void build_C(const float* __restrict__ r,
                                               const v2f* __restrict__ twg,
                                               v2f* __restrict__ CgT) {
  __shared__ v2f d[PAD(NFFT - 1) + 1];
  const int t = threadIdx.x;
  for (int i = t; i < NFFT; i += 256)
    d[PAD(i)] = (v2f){r[(NFFT - i) & (NFFT - 1)], 0.f};
  __syncthreads();
  fwd_stage8<512>(d, twg, t); fwd_stage8<512>(d, twg, t + 256); __syncthreads();
  fwd_stage8<64>(d, twg, t);  fwd_stage8<64>(d, twg, t + 256);  __syncthreads();
  fwd_stage8<8>(d, twg, t);   fwd_stage8<8>(d, twg, t + 256);   __syncthreads();
#pragma unroll
  for (int v = 0; v < 2; ++v) {
    const int u = t + 256 * v;
    v2f a[8];
#pragma unroll
    for (int q = 0; q < 8; ++q) a[q] = d[PAD(8 * u + q)];
    fft8(a);
#pragma unroll
    for (int q = 0; q < 8; ++q) CgT[q * 512 + u] = a[q];
  }
}

// -------- kernel 2: packed 2-row radix-8 FFT convolution, 512 threads --------
__global__ __launch_bounds__(512) void fft_conv8(
    const float* __restrict__ x, const v2f* __restrict__ CgT,
    const v2f* __restrict__ twg, const float* __restrict__ bias,
    float* __restrict__ y) {
  __shared__ v2f d[PAD(NFFT - 1) + 1];
  const int t = threadIdx.x;  // 0..511
  const size_t r0 = 2 * (size_t)blockIdx.x;
  const float4* x04 = (const float4*)(x + r0 * NFFT);
  const float4* x14 = (const float4*)(x + (r0 + 1) * NFFT);
  const float4* b4 = (const float4*)bias;
  float4* y04 = (float4*)(y + r0 * NFFT);
  float4* y14 = (float4*)(y + (r0 + 1) * NFFT);

  // ---- load: float4 from global -> packed complex in LDS ----
#pragma unroll
  for (int w = 0; w < 2; ++w) {
    const int i4 = t + 512 * w;
    const float4 v0 = x04[i4];
    const float4 v1 = x14[i4];
    const int i0 = i4 * 4;
    d[PAD(i0 + 0)] = (v2f){v0.x, v1.x};
    d[PAD(i0 + 1)] = (v2f){v0.y, v1.y};
    d[PAD(i0 + 2)] = (v2f){v0.z, v1.z};
    d[PAD(i0 + 3)] = (v2f){v0.w, v1.w};
  }
  __syncthreads();

  // ---- forward DIF (one butterfly per thread) ----
  fwd_stage8<512>(d, twg, t); __syncthreads();
  fwd_stage8<64>(d, twg, t);  __syncthreads();
  fwd_stage8<8>(d, twg, t);   __syncthreads();

  // ---- fused fwd<1> + pointwise(CgT) + inv<1>, all in registers ----
  {
    v2f a[8];
#pragma unroll
    for (int q = 0; q < 8; ++q) a[q] = d[PAD(8 * t + q)];
    fft8(a);
#pragma unroll
    for (int q = 0; q < 8; ++q) a[q] = cmul(a[q], CgT[q * 512 + t]);
    ifft8(a);
#pragma unroll
    for (int q = 0; q < 8; ++q) d[PAD(8 * t + q)] = a[q];
  }
  __syncthreads();

  // ---- inverse DIT ----
  inv_stage8<8>(d, twg, t);   __syncthreads();
  inv_stage8<64>(d, twg, t);  __syncthreads();
  inv_stage8<512>(d, twg, t); __syncthreads();

  // ---- store: LDS -> float4 to global (Re -> row0, Im -> row1) ----
  const float s = 1.0f / (float)NFFT;
#pragma unroll
  for (int w = 0; w < 2; ++w) {
    const int i4 = t + 512 * w;
    const int i0 = i4 * 4;
    const float4 bv = b4[i4];
    const v2f d0 = d[PAD(i0 + 0)];
    const v2f d1 = d[PAD(i0 + 1)];
    const v2f d2 = d[PAD(i0 + 2)];
    const v2f d3 = d[PAD(i0 + 3)];
    float4 o0, o1;
    o0.x = d0.x * s + bv.x; o1.x = d0.y * s + bv.x;
    o0.y = d1.x * s + bv.y; o1.y = d1.y * s + bv.y;
    o0.z = d2.x * s + bv.z; o1.z = d2.y * s + bv.z;
    o0.w = d3.x * s + bv.w; o1.w = d3.y * s + bv.w;
    y04[i4] = o0;
    y14[i4] = o1;
  }
}

// ---------------- fallback GEMM (no ws / odd shapes) ----------------

typedef __attribute__((ext_vector_type(8))) short bf16x8;

__device__ __forceinline__ unsigned short f2bf(float f) {
  union { __hip_bfloat16 h; unsigned short u; } v;
  v.h = __float2bfloat16(f);
  return v.u;
}

#define LDP 72

__global__ __launch_bounds__(256) void circ_gemm_fb(
    const float* __restrict__ x, const float* __restrict__ r,
    const float* __restrict__ bias, float* __restrict__ y, int n) {
  __shared__ unsigned short Asf[128][LDP];
  __shared__ unsigned short Bsf[128][LDP];

  const int tid = threadIdx.x;
  const int wid = tid >> 6;
  const int lane = tid & 63;
  const int bm0 = blockIdx.y * 128;
  const int bn0 = blockIdx.x * 128;
  const int m0w = (wid >> 1) * 64;
  const int n0w = (wid & 1) * 64;
  const int lr = lane & 15;
  const int lk = (lane >> 4) * 8;
  const int mask = n - 1;

  f32x4 acc[4][4];
#pragma unroll
  for (int i = 0; i < 4; ++i)
#pragma unroll
    for (int j = 0; j < 4; ++j) acc[i][j] = (f32x4){0.f, 0.f, 0.f, 0.f};

  const int arow = tid >> 4;
  const int acol = (tid & 15) * 4;
  const int bnn = tid >> 1;
  const int bk0 = (tid & 1) * 32;

  for (int k0 = 0; k0 < n; k0 += 64) {
#pragma unroll
    for (int p = 0; p < 8; ++p) {
      const float4 v =
          *(const float4*)&x[(size_t)(bm0 + arow + p * 16) * n + k0 + acol];
      us4 hh;
      hh.x = f2bf(v.x); hh.y = f2bf(v.y); hh.z = f2bf(v.z); hh.w = f2bf(v.w);
      *(us4*)&Asf[arow + p * 16][acol] = hh;
    }
    {
      const int base = k0 + bk0 - bn0 - bnn;
#pragma unroll
      for (int kq = 0; kq < 32; kq += 4) {
        us4 hh;
        hh.x = f2bf(r[(base + kq + 0) & mask]);
        hh.y = f2bf(r[(base + kq + 1) & mask]);
        hh.z = f2bf(r[(base + kq + 2) & mask]);
        hh.w = f2bf(r[(base + kq + 3) & mask]);
        *(us4*)&Bsf[bnn][bk0 + kq] = hh;
      }
    }
    __syncthreads();

#pragma unroll
    for (int kk = 0; kk < 2; ++kk) {
      bf16x8 af[4], bfr[4];
#pragma unroll
      for (int mi = 0; mi < 4; ++mi)
        af[mi] = *(const bf16x8*)&Asf[m0w + mi * 16 + lr][kk * 32 + lk];
#pragma unroll
      for (int ni = 0; ni < 4; ++ni)
        bfr[ni] = *(const bf16x8*)&Bsf[n0w + ni * 16 + lr][kk * 32 + lk];
#pragma unroll
      for (int mi = 0; mi < 4; ++mi)
#pragma unroll
        for (int ni = 0; ni < 4; ++ni)
          acc[mi][ni] = __builtin_amdgcn_mfma_f32_16x16x32_bf16(
              af[mi], bfr[ni], acc[mi][ni], 0, 0, 0);
    }
    __syncthreads();
  }

#pragma unroll
  for (int ni = 0; ni < 4; ++ni) {
    const int col = bn0 + n0w + ni * 16 + lr;
    const float bv = bias[col];
#pragma unroll
    for (int mi = 0; mi < 4; ++mi) {
      const int row0 = bm0 + m0w + mi * 16 + (lane >> 4) * 4;
#pragma unroll
      for (int j = 0; j < 4; ++j)
        y[(size_t)(row0 + j) * n + col] = acc[mi][ni][j] + bv;
    }
  }
}

// ---------------- launch ----------------

extern "C" void kernel_launch(void* const* d_in, const int* in_sizes, int n_in,
                              void* d_out, int out_size, void* d_ws,
                              size_t ws_size, hipStream_t stream) {
  const float* x = (const float*)d_in[0];
  const float* r = (const float*)d_in[1];
  const float* b = (const float*)d_in[2];
  float* y = (float*)d_out;
  const int n = in_sizes[1];          // 4096
  const int batch = in_sizes[0] / n;  // 8192

  if (n == NFFT && (batch & 1) == 0 && ws_size >= 2 * NFFT * sizeof(v2f)) {
    v2f* twg = (v2f*)d_ws;
    v2f* CgT = twg + NFFT;
    build_tw<<<NFFT / 256, 256, 0, stream>>>(twg);
    build_C<<<1, 256, 0, stream>>>(r, twg, CgT);
    fft_conv8<<<batch / 2, 512, 0, stream>>>(x, CgT, twg, b, y);
  } else {
    dim3 grid(n / 128, batch / 128);
    circ_gemm_fb<<<grid, 256, 0, stream>>>(x, r, b, y, n);
  }
}

// Round 15
// 75.072 us; speedup vs baseline: 3.5139x; 1.0649x over previous
//
#include <hip/hip_runtime.h>
#include <hip/hip_bf16.h>
#include <math.h>

// y[b,i] = sum_j x[b,j] * r[(j-i) mod N] + bias[i]
//        = circular conv: y = IFFT(FFT(x) * FFT(c)) + bias, c[k] = r[(-k) mod N]
// Radix-8 FFT (N=4096 = 8^4), fp32, in-LDS, two rows packed per FFT.
//   - VOP3P packed fp32 inline asm for all complex math (R14)
//   - F512 reads x DIRECTLY from global (coalesced scalar); I512 writes y
//     DIRECTLY with fused bias -> LDS touches/elem 16 -> 12, barriers 8 -> 6
//   - 1/N folded into CgT at build time
//   - 512 threads/block, one butterfly/thread/stage; tree twiddle powers
//   - PAD(i)=i+(i>>4)

#define NFFT 4096
#define PAD(i) ((i) + ((i) >> 4))

typedef __attribute__((ext_vector_type(2))) float v2f;
typedef __attribute__((ext_vector_type(4))) float f32x4;
typedef __attribute__((ext_vector_type(4))) unsigned short us4;

#define RQ 0.70710678118654752f

// ---- VOP3P packed-fp32 primitives (verified R14) ----
__device__ __forceinline__ v2f padd(v2f a, v2f b) {
  v2f r;
  asm("v_pk_add_f32 %0, %1, %2" : "=v"(r) : "v"(a), "v"(b));
  return r;
}
__device__ __forceinline__ v2f psub(v2f a, v2f b) {
  v2f r;
  asm("v_pk_add_f32 %0, %1, %2 neg_lo:[0,1] neg_hi:[0,1]"
      : "=v"(r) : "v"(a), "v"(b));
  return r;
}
__device__ __forceinline__ v2f pmul(v2f a, v2f b) {
  v2f r;
  asm("v_pk_mul_f32 %0, %1, %2" : "=v"(r) : "v"(a), "v"(b));
  return r;
}
// a + (-i)*b = {a.x + b.y, a.y - b.x}
__device__ __forceinline__ v2f addmni(v2f a, v2f b) {
  v2f r;
  asm("v_pk_add_f32 %0, %1, %2 op_sel:[0,1] op_sel_hi:[1,0] neg_hi:[0,1]"
      : "=v"(r) : "v"(a), "v"(b));
  return r;
}
// a + (+i)*b = {a.x - b.y, a.y + b.x}
__device__ __forceinline__ v2f addmpi(v2f a, v2f b) {
  v2f r;
  asm("v_pk_add_f32 %0, %1, %2 op_sel:[0,1] op_sel_hi:[1,0] neg_lo:[0,1]"
      : "=v"(r) : "v"(a), "v"(b));
  return r;
}
// complex a*b: t={ax*bx, ax*by}; r={t.lo - ay*by, t.hi + ay*bx}
__device__ __forceinline__ v2f cmul(v2f a, v2f b) {
  v2f t, r;
  asm("v_pk_mul_f32 %0, %1, %2 op_sel:[0,0] op_sel_hi:[0,1]"
      : "=v"(t) : "v"(a), "v"(b));
  asm("v_pk_fma_f32 %0, %1, %2, %3 op_sel:[1,1,0] op_sel_hi:[1,0,1] neg_lo:[1,0,0]"
      : "=v"(r) : "v"(a), "v"(b), "v"(t));
  return r;
}
// complex a*conj(b): t={ax*bx, ay*bx}; r={t.lo + ay*by, t.hi - ax*by}
__device__ __forceinline__ v2f cmulj(v2f a, v2f b) {
  v2f t, r;
  asm("v_pk_mul_f32 %0, %1, %2 op_sel:[0,0] op_sel_hi:[1,0]"
      : "=v"(t) : "v"(a), "v"(b));
  asm("v_pk_fma_f32 %0, %1, %2, %3 op_sel:[1,1,0] op_sel_hi:[0,1,1] neg_hi:[1,0,0]"
      : "=v"(r) : "v"(a), "v"(b), "v"(t));
  return r;
}

// forward 8-point DFT, natural order (verified R14)
__device__ __forceinline__ void fft8(v2f a[8]) {
  const v2f rq2 = {RQ, RQ};
  v2f es0 = padd(a[0], a[4]), ed0 = psub(a[0], a[4]);
  v2f es1 = padd(a[2], a[6]), ed1 = psub(a[2], a[6]);
  v2f E0 = padd(es0, es1), E2 = psub(es0, es1);
  v2f E1 = addmni(ed0, ed1), E3 = addmpi(ed0, ed1);
  v2f os0 = padd(a[1], a[5]), od0 = psub(a[1], a[5]);
  v2f os1 = padd(a[3], a[7]), od1 = psub(a[3], a[7]);
  v2f O0 = padd(os0, os1), O2 = psub(os0, os1);
  v2f O1 = addmni(od0, od1), O3 = addmpi(od0, od1);
  O1 = pmul(addmni(O1, O1), rq2);         // RQ*(1-i)*O1
  v2f u3 = pmul(addmpi(O3, O3), rq2);     // RQ*(1+i)*O3 ; O3' = -u3
  a[0] = padd(E0, O0); a[4] = psub(E0, O0);
  a[1] = padd(E1, O1); a[5] = psub(E1, O1);
  a[2] = addmni(E2, O2); a[6] = addmpi(E2, O2);  // fold O2*(-i)
  a[3] = psub(E3, u3); a[7] = padd(E3, u3);
}

// inverse 8-point DFT, natural order, unscaled (verified R14)
__device__ __forceinline__ void ifft8(v2f z[8]) {
  const v2f rq2 = {RQ, RQ};
  v2f es0 = padd(z[0], z[4]), ed0 = psub(z[0], z[4]);
  v2f es1 = padd(z[2], z[6]), ed1 = psub(z[2], z[6]);
  v2f E0 = padd(es0, es1), E2 = psub(es0, es1);
  v2f E1 = addmpi(ed0, ed1), E3 = addmni(ed0, ed1);
  v2f os0 = padd(z[1], z[5]), od0 = psub(z[1], z[5]);
  v2f os1 = padd(z[3], z[7]), od1 = psub(z[3], z[7]);
  v2f O0 = padd(os0, os1), O2 = psub(os0, os1);
  v2f O1 = addmpi(od0, od1), O3 = addmni(od0, od1);
  O1 = pmul(addmpi(O1, O1), rq2);         // RQ*(1+i)*O1
  v2f u3 = pmul(addmni(O3, O3), rq2);     // RQ*(1-i)*O3 ; O3' = -u3
  z[0] = padd(E0, O0); z[4] = psub(E0, O0);
  z[1] = padd(E1, O1); z[5] = psub(E1, O1);
  z[2] = addmpi(E2, O2); z[6] = addmni(E2, O2);  // fold O2*(+i)
  z[3] = psub(E3, u3); z[7] = padd(E3, u3);
}

// ---- forward DIF radix-8 stage: ONE butterfly (index u), LDS->LDS ----
template <int M>
__device__ __forceinline__ void fwd_stage8(v2f* d, const v2f* __restrict__ twg,
                                           int u) {
  constexpr int STEP = NFFT / (8 * M);
  const int n = u & (M - 1);
  const int base = ((u & ~(M - 1)) << 3) + n;
  v2f a[8];
#pragma unroll
  for (int q = 0; q < 8; ++q) a[q] = d[PAD(base + q * M)];
  fft8(a);
  const v2f b = twg[n * STEP];
  const v2f p2 = cmul(b, b);
  const v2f p3 = cmul(p2, b);
  const v2f p4 = cmul(p2, p2);
  const v2f p5 = cmul(p3, p2);
  const v2f p6 = cmul(p3, p3);
  const v2f p7 = cmul(p4, p3);
  d[PAD(base)] = a[0];
  d[PAD(base + 1 * M)] = cmul(a[1], b);
  d[PAD(base + 2 * M)] = cmul(a[2], p2);
  d[PAD(base + 3 * M)] = cmul(a[3], p3);
  d[PAD(base + 4 * M)] = cmul(a[4], p4);
  d[PAD(base + 5 * M)] = cmul(a[5], p5);
  d[PAD(base + 6 * M)] = cmul(a[6], p6);
  d[PAD(base + 7 * M)] = cmul(a[7], p7);
}

// ---- inverse DIT radix-8 stage: ONE butterfly (index u), LDS->LDS ----
template <int M>
__device__ __forceinline__ void inv_stage8(v2f* d, const v2f* __restrict__ twg,
                                           int u) {
  constexpr int STEP = NFFT / (8 * M);
  const int n = u & (M - 1);
  const int base = ((u & ~(M - 1)) << 3) + n;
  const v2f b = twg[n * STEP];
  const v2f p2 = cmul(b, b);
  const v2f p3 = cmul(p2, b);
  const v2f p4 = cmul(p2, p2);
  const v2f p5 = cmul(p3, p2);
  const v2f p6 = cmul(p3, p3);
  const v2f p7 = cmul(p4, p3);
  v2f z[8];
  z[0] = d[PAD(base)];
  z[1] = cmulj(d[PAD(base + 1 * M)], b);
  z[2] = cmulj(d[PAD(base + 2 * M)], p2);
  z[3] = cmulj(d[PAD(base + 3 * M)], p3);
  z[4] = cmulj(d[PAD(base + 4 * M)], p4);
  z[5] = cmulj(d[PAD(base + 5 * M)], p5);
  z[6] = cmulj(d[PAD(base + 6 * M)], p6);
  z[7] = cmulj(d[PAD(base + 7 * M)], p7);
  ifft8(z);
#pragma unroll
  for (int q = 0; q < 8; ++q) d[PAD(base + q * M)] = z[q];
}

// ---------------- kernel 0: twiddle table tw[j] = e^{-2pi i j/N} ----------------
__global__ __launch_bounds__(256) void build_tw(v2f* __restrict__ twg) {
  const int j = blockIdx.x * 256 + threadIdx.x;
  if (j < NFFT) {
    double ang = (-2.0 * 3.14159265358979323846) * (double)j / (double)NFFT;
    twg[j] = (v2f){(float)cos(ang), (float)sin(ang)};
  }
}

// -- kernel 1: CgT[q*512+u] = (fwd chain of c)[8u+q] * (1/N), q-major --
__global__ __launch_bounds__(256) void build_C(const float* __restrict__ r,
                                               const v2f* __restrict__ twg,
                                               v2f* __restrict__ CgT) {
  __shared__ v2f d[PAD(NFFT - 1) + 1];
  const int t = threadIdx.x;
  for (int i = t; i < NFFT; i += 256)
    d[PAD(i)] = (v2f){r[(NFFT - i) & (NFFT - 1)], 0.f};
  __syncthreads();
  fwd_stage8<512>(d, twg, t); fwd_stage8<512>(d, twg, t + 256); __syncthreads();
  fwd_stage8<64>(d, twg, t);  fwd_stage8<64>(d, twg, t + 256);  __syncthreads();
  fwd_stage8<8>(d, twg, t);   fwd_stage8<8>(d, twg, t + 256);   __syncthreads();
  const float s = 1.0f / (float)NFFT;
#pragma unroll
  for (int v = 0; v < 2; ++v) {
    const int u = t + 256 * v;
    v2f a[8];
#pragma unroll
    for (int q = 0; q < 8; ++q) a[q] = d[PAD(8 * u + q)];
    fft8(a);
#pragma unroll
    for (int q = 0; q < 8; ++q) CgT[q * 512 + u] = (v2f){a[q].x * s, a[q].y * s};
  }
}

// -------- kernel 2: packed 2-row radix-8 FFT conv, direct-global ends --------
__global__ __launch_bounds__(512) void fft_conv9(
    const float* __restrict__ x, const v2f* __restrict__ CgT,
    const v2f* __restrict__ twg, const float* __restrict__ bias,
    float* __restrict__ y) {
  __shared__ v2f d[PAD(NFFT - 1) + 1];
  const int t = threadIdx.x;  // 0..511
  const size_t r0 = 2 * (size_t)blockIdx.x;
  const float* x0 = x + r0 * NFFT;
  const float* x1 = x0 + NFFT;
  float* y0 = y + r0 * NFFT;
  float* y1 = y0 + NFFT;

  // ---- F512 fused with global load: x[t+512q] scalar coalesced ----
  {
    v2f a[8];
#pragma unroll
    for (int q = 0; q < 8; ++q)
      a[q] = (v2f){x0[t + 512 * q], x1[t + 512 * q]};
    fft8(a);
    const v2f b = twg[t];  // n = t, STEP = 1
    const v2f p2 = cmul(b, b);
    const v2f p3 = cmul(p2, b);
    const v2f p4 = cmul(p2, p2);
    const v2f p5 = cmul(p3, p2);
    const v2f p6 = cmul(p3, p3);
    const v2f p7 = cmul(p4, p3);
    d[PAD(t)] = a[0];
    d[PAD(t + 1 * 512)] = cmul(a[1], b);
    d[PAD(t + 2 * 512)] = cmul(a[2], p2);
    d[PAD(t + 3 * 512)] = cmul(a[3], p3);
    d[PAD(t + 4 * 512)] = cmul(a[4], p4);
    d[PAD(t + 5 * 512)] = cmul(a[5], p5);
    d[PAD(t + 6 * 512)] = cmul(a[6], p6);
    d[PAD(t + 7 * 512)] = cmul(a[7], p7);
  }
  __syncthreads();

  fwd_stage8<64>(d, twg, t); __syncthreads();
  fwd_stage8<8>(d, twg, t);  __syncthreads();

  // ---- fused fwd<1> + pointwise(CgT, pre-scaled by 1/N) + inv<1> ----
  {
    v2f a[8];
#pragma unroll
    for (int q = 0; q < 8; ++q) a[q] = d[PAD(8 * t + q)];
    fft8(a);
#pragma unroll
    for (int q = 0; q < 8; ++q) a[q] = cmul(a[q], CgT[q * 512 + t]);
    ifft8(a);
#pragma unroll
    for (int q = 0; q < 8; ++q) d[PAD(8 * t + q)] = a[q];
  }
  __syncthreads();

  inv_stage8<8>(d, twg, t);  __syncthreads();
  inv_stage8<64>(d, twg, t); __syncthreads();

  // ---- I512 fused with global store: y[t+512q] scalar coalesced + bias ----
  {
    const v2f b = twg[t];
    const v2f p2 = cmul(b, b);
    const v2f p3 = cmul(p2, b);
    const v2f p4 = cmul(p2, p2);
    const v2f p5 = cmul(p3, p2);
    const v2f p6 = cmul(p3, p3);
    const v2f p7 = cmul(p4, p3);
    v2f z[8];
    z[0] = d[PAD(t)];
    z[1] = cmulj(d[PAD(t + 1 * 512)], b);
    z[2] = cmulj(d[PAD(t + 2 * 512)], p2);
    z[3] = cmulj(d[PAD(t + 3 * 512)], p3);
    z[4] = cmulj(d[PAD(t + 4 * 512)], p4);
    z[5] = cmulj(d[PAD(t + 5 * 512)], p5);
    z[6] = cmulj(d[PAD(t + 6 * 512)], p6);
    z[7] = cmulj(d[PAD(t + 7 * 512)], p7);
    ifft8(z);
#pragma unroll
    for (int q = 0; q < 8; ++q) {
      const int idx = t + 512 * q;
      const float bv = bias[idx];
      y0[idx] = z[q].x + bv;
      y1[idx] = z[q].y + bv;
    }
  }
}

// ---------------- fallback GEMM (no ws / odd shapes) ----------------

typedef __attribute__((ext_vector_type(8))) short bf16x8;

__device__ __forceinline__ unsigned short f2bf(float f) {
  union { __hip_bfloat16 h; unsigned short u; } v;
  v.h = __float2bfloat16(f);
  return v.u;
}

#define LDP 72

__global__ __launch_bounds__(256) void circ_gemm_fb(
    const float* __restrict__ x, const float* __restrict__ r,
    const float* __restrict__ bias, float* __restrict__ y, int n) {
  __shared__ unsigned short Asf[128][LDP];
  __shared__ unsigned short Bsf[128][LDP];

  const int tid = threadIdx.x;
  const int wid = tid >> 6;
  const int lane = tid & 63;
  const int bm0 = blockIdx.y * 128;
  const int bn0 = blockIdx.x * 128;
  const int m0w = (wid >> 1) * 64;
  const int n0w = (wid & 1) * 64;
  const int lr = lane & 15;
  const int lk = (lane >> 4) * 8;
  const int mask = n - 1;

  f32x4 acc[4][4];
#pragma unroll
  for (int i = 0; i < 4; ++i)
#pragma unroll
    for (int j = 0; j < 4; ++j) acc[i][j] = (f32x4){0.f, 0.f, 0.f, 0.f};

  const int arow = tid >> 4;
  const int acol = (tid & 15) * 4;
  const int bnn = tid >> 1;
  const int bk0 = (tid & 1) * 32;

  for (int k0 = 0; k0 < n; k0 += 64) {
#pragma unroll
    for (int p = 0; p < 8; ++p) {
      const float4 v =
          *(const float4*)&x[(size_t)(bm0 + arow + p * 16) * n + k0 + acol];
      us4 hh;
      hh.x = f2bf(v.x); hh.y = f2bf(v.y); hh.z = f2bf(v.z); hh.w = f2bf(v.w);
      *(us4*)&Asf[arow + p * 16][acol] = hh;
    }
    {
      const int base = k0 + bk0 - bn0 - bnn;
#pragma unroll
      for (int kq = 0; kq < 32; kq += 4) {
        us4 hh;
        hh.x = f2bf(r[(base + kq + 0) & mask]);
        hh.y = f2bf(r[(base + kq + 1) & mask]);
        hh.z = f2bf(r[(base + kq + 2) & mask]);
        hh.w = f2bf(r[(base + kq + 3) & mask]);
        *(us4*)&Bsf[bnn][bk0 + kq] = hh;
      }
    }
    __syncthreads();

#pragma unroll
    for (int kk = 0; kk < 2; ++kk) {
      bf16x8 af[4], bfr[4];
#pragma unroll
      for (int mi = 0; mi < 4; ++mi)
        af[mi] = *(const bf16x8*)&Asf[m0w + mi * 16 + lr][kk * 32 + lk];
#pragma unroll
      for (int ni = 0; ni < 4; ++ni)
        bfr[ni] = *(const bf16x8*)&Bsf[n0w + ni * 16 + lr][kk * 32 + lk];
#pragma unroll
      for (int mi = 0; mi < 4; ++mi)
#pragma unroll
        for (int ni = 0; ni < 4; ++ni)
          acc[mi][ni] = __builtin_amdgcn_mfma_f32_16x16x32_bf16(
              af[mi], bfr[ni], acc[mi][ni], 0, 0, 0);
    }
    __syncthreads();
  }

#pragma unroll
  for (int ni = 0; ni < 4; ++ni) {
    const int col = bn0 + n0w + ni * 16 + lr;
    const float bv = bias[col];
#pragma unroll
    for (int mi = 0; mi < 4; ++mi) {
      const int row0 = bm0 + m0w + mi * 16 + (lane >> 4) * 4;
#pragma unroll
      for (int j = 0; j < 4; ++j)
        y[(size_t)(row0 + j) * n + col] = acc[mi][ni][j] + bv;
    }
  }
}

// ---------------- launch ----------------

extern "C" void kernel_launch(void* const* d_in, const int* in_sizes, int n_in,
                              void* d_out, int out_size, void* d_ws,
                              size_t ws_size, hipStream_t stream) {
  const float* x = (const float*)d_in[0];
  const float* r = (const float*)d_in[1];
  const float* b = (const float*)d_in[2];
  float* y = (float*)d_out;
  const int n = in_sizes[1];          // 4096
  const int batch = in_sizes[0] / n;  // 8192

  if (n == NFFT && (batch & 1) == 0 && ws_size >= 2 * NFFT * sizeof(v2f)) {
    v2f* twg = (v2f*)d_ws;
    v2f* CgT = twg + NFFT;
    build_tw<<<NFFT / 256, 256, 0, stream>>>(twg);
    build_C<<<1, 256, 0, stream>>>(r, twg, CgT);
    fft_conv9<<<batch / 2, 512, 0, stream>>>(x, CgT, twg, b, y);
  } else {
    dim3 grid(n / 128, batch / 128);
    circ_gemm_fb<<<grid, 256, 0, stream>>>(x, r, b, y, n);
  }
}

// Round 16
// 62.701 us; speedup vs baseline: 4.2072x; 1.1973x over previous
//
#include <hip/hip_runtime.h>
#include <hip/hip_bf16.h>
#include <math.h>

// y[b,i] = sum_j x[b,j] * r[(j-i) mod N] + bias[i]
//        = circular conv: y = IFFT(FFT(x) * FFT(c)) + bias, c[k] = r[(-k) mod N]
// Radix-16 FFT (N=4096 = 16^3), fp32, in-LDS, two rows packed per FFT.
//   - 3 fwd + 3 inv stages; outer stages fused with DIRECT global I/O
//   - 5 stage-passes, 8 LDS touches/elem, 4 barriers (radix-8 had 7/12/6)
//   - all complex math via R14-verified VOP3P pk-asm primitives
//   - fft16 = 8x pk-fft4 + 9 const cmuls; G[2][2]*(-/+i) folded into pass-2
//   - __launch_bounds__(256,2): prevents the VGPR-spill that sank R9/R10
//   - 1/N folded into CgT; PAD(i)=i+(i>>4)

#define NFFT 4096
#define PAD(i) ((i) + ((i) >> 4))

typedef __attribute__((ext_vector_type(2))) float v2f;
typedef __attribute__((ext_vector_type(4))) float f32x4;
typedef __attribute__((ext_vector_type(4))) unsigned short us4;

#define RQ 0.70710678118654752f
#define C1 0.9238795325112867f
#define S1 0.3826834323650898f

// ---- VOP3P packed-fp32 primitives (HW-verified R14/R15) ----
__device__ __forceinline__ v2f padd(v2f a, v2f b) {
  v2f r;
  asm("v_pk_add_f32 %0, %1, %2" : "=v"(r) : "v"(a), "v"(b));
  return r;
}
__device__ __forceinline__ v2f psub(v2f a, v2f b) {
  v2f r;
  asm("v_pk_add_f32 %0, %1, %2 neg_lo:[0,1] neg_hi:[0,1]"
      : "=v"(r) : "v"(a), "v"(b));
  return r;
}
// a + (-i)*b = {a.x + b.y, a.y - b.x}
__device__ __forceinline__ v2f addmni(v2f a, v2f b) {
  v2f r;
  asm("v_pk_add_f32 %0, %1, %2 op_sel:[0,1] op_sel_hi:[1,0] neg_hi:[0,1]"
      : "=v"(r) : "v"(a), "v"(b));
  return r;
}
// a + (+i)*b = {a.x - b.y, a.y + b.x}
__device__ __forceinline__ v2f addmpi(v2f a, v2f b) {
  v2f r;
  asm("v_pk_add_f32 %0, %1, %2 op_sel:[0,1] op_sel_hi:[1,0] neg_lo:[0,1]"
      : "=v"(r) : "v"(a), "v"(b));
  return r;
}
// complex a*b
__device__ __forceinline__ v2f cmul(v2f a, v2f b) {
  v2f t, r;
  asm("v_pk_mul_f32 %0, %1, %2 op_sel:[0,0] op_sel_hi:[0,1]"
      : "=v"(t) : "v"(a), "v"(b));
  asm("v_pk_fma_f32 %0, %1, %2, %3 op_sel:[1,1,0] op_sel_hi:[1,0,1] neg_lo:[1,0,0]"
      : "=v"(r) : "v"(a), "v"(b), "v"(t));
  return r;
}
// complex a*conj(b)
__device__ __forceinline__ v2f cmulj(v2f a, v2f b) {
  v2f t, r;
  asm("v_pk_mul_f32 %0, %1, %2 op_sel:[0,0] op_sel_hi:[1,0]"
      : "=v"(t) : "v"(a), "v"(b));
  asm("v_pk_fma_f32 %0, %1, %2, %3 op_sel:[1,1,0] op_sel_hi:[0,1,1] neg_hi:[1,0,0]"
      : "=v"(r) : "v"(a), "v"(b), "v"(t));
  return r;
}

// ---- 4-point DFT building blocks (in-place, by reference) ----
__device__ __forceinline__ void fft4(v2f& x0, v2f& x1, v2f& x2, v2f& x3) {
  v2f t0 = padd(x0, x2), t1 = psub(x0, x2);
  v2f t2 = padd(x1, x3), t3 = psub(x1, x3);
  x0 = padd(t0, t2); x1 = addmni(t1, t3);
  x2 = psub(t0, t2); x3 = addmpi(t1, t3);
}
__device__ __forceinline__ void ifft4(v2f& x0, v2f& x1, v2f& x2, v2f& x3) {
  v2f t0 = padd(x0, x2), t1 = psub(x0, x2);
  v2f t2 = padd(x1, x3), t3 = psub(x1, x3);
  x0 = padd(t0, t2); x1 = addmpi(t1, t3);
  x2 = psub(t0, t2); x3 = addmni(t1, t3);
}

// ---- natural-order 16-point DFT (structure HW-verified in R9/R10) ----
// pass1: G[r][k] = fft4_c(a[r+4c]) stored at a[r+4k]; twiddle w^{rk};
// pass2: X[k1+4k2] = fft4_r(G[r][k1]); G[2][2]*w^4 folds into pass2.
__device__ __forceinline__ void fft16(v2f a[16]) {
  fft4(a[0], a[4], a[8], a[12]);
  fft4(a[1], a[5], a[9], a[13]);
  fft4(a[2], a[6], a[10], a[14]);
  fft4(a[3], a[7], a[11], a[15]);
  const v2f W1 = {C1, -S1}, W2 = {RQ, -RQ}, W3 = {S1, -C1};
  const v2f W6 = {-RQ, -RQ}, W9 = {-C1, S1};
  a[5] = cmul(a[5], W1);  a[9] = cmul(a[9], W2);   a[13] = cmul(a[13], W3);
  a[6] = cmul(a[6], W2);  /* a[10]: *(-i) folded */ a[14] = cmul(a[14], W6);
  a[7] = cmul(a[7], W3);  a[11] = cmul(a[11], W6); a[15] = cmul(a[15], W9);
  v2f x[16];
  // k1=0: inputs a[0..3]
  {
    v2f t0 = padd(a[0], a[2]), t1 = psub(a[0], a[2]);
    v2f t2 = padd(a[1], a[3]), t3 = psub(a[1], a[3]);
    x[0] = padd(t0, t2); x[4] = addmni(t1, t3);
    x[8] = psub(t0, t2); x[12] = addmpi(t1, t3);
  }
  // k1=1: inputs a[4..7]
  {
    v2f t0 = padd(a[4], a[6]), t1 = psub(a[4], a[6]);
    v2f t2 = padd(a[5], a[7]), t3 = psub(a[5], a[7]);
    x[1] = padd(t0, t2); x[5] = addmni(t1, t3);
    x[9] = psub(t0, t2); x[13] = addmpi(t1, t3);
  }
  // k1=2: inputs a[8..11]; a[10] is raw G[2][2], needs *(-i): fold
  {
    v2f t0 = addmni(a[8], a[10]), t1 = addmpi(a[8], a[10]);
    v2f t2 = padd(a[9], a[11]), t3 = psub(a[9], a[11]);
    x[2] = padd(t0, t2); x[6] = addmni(t1, t3);
    x[10] = psub(t0, t2); x[14] = addmpi(t1, t3);
  }
  // k1=3: inputs a[12..15]
  {
    v2f t0 = padd(a[12], a[14]), t1 = psub(a[12], a[14]);
    v2f t2 = padd(a[13], a[15]), t3 = psub(a[13], a[15]);
    x[3] = padd(t0, t2); x[7] = addmni(t1, t3);
    x[11] = psub(t0, t2); x[15] = addmpi(t1, t3);
  }
#pragma unroll
  for (int q = 0; q < 16; ++q) a[q] = x[q];
}

__device__ __forceinline__ void ifft16(v2f a[16]) {
  ifft4(a[0], a[4], a[8], a[12]);
  ifft4(a[1], a[5], a[9], a[13]);
  ifft4(a[2], a[6], a[10], a[14]);
  ifft4(a[3], a[7], a[11], a[15]);
  const v2f W1 = {C1, -S1}, W2 = {RQ, -RQ}, W3 = {S1, -C1};
  const v2f W6 = {-RQ, -RQ}, W9 = {-C1, S1};
  a[5] = cmulj(a[5], W1);  a[9] = cmulj(a[9], W2);   a[13] = cmulj(a[13], W3);
  a[6] = cmulj(a[6], W2);  /* a[10]: *(+i) folded */  a[14] = cmulj(a[14], W6);
  a[7] = cmulj(a[7], W3);  a[11] = cmulj(a[11], W6); a[15] = cmulj(a[15], W9);
  v2f x[16];
  {
    v2f t0 = padd(a[0], a[2]), t1 = psub(a[0], a[2]);
    v2f t2 = padd(a[1], a[3]), t3 = psub(a[1], a[3]);
    x[0] = padd(t0, t2); x[4] = addmpi(t1, t3);
    x[8] = psub(t0, t2); x[12] = addmni(t1, t3);
  }
  {
    v2f t0 = padd(a[4], a[6]), t1 = psub(a[4], a[6]);
    v2f t2 = padd(a[5], a[7]), t3 = psub(a[5], a[7]);
    x[1] = padd(t0, t2); x[5] = addmpi(t1, t3);
    x[9] = psub(t0, t2); x[13] = addmni(t1, t3);
  }
  {
    v2f t0 = addmpi(a[8], a[10]), t1 = addmni(a[8], a[10]);
    v2f t2 = padd(a[9], a[11]), t3 = psub(a[9], a[11]);
    x[2] = padd(t0, t2); x[6] = addmpi(t1, t3);
    x[10] = psub(t0, t2); x[14] = addmni(t1, t3);
  }
  {
    v2f t0 = padd(a[12], a[14]), t1 = psub(a[12], a[14]);
    v2f t2 = padd(a[13], a[15]), t3 = psub(a[13], a[15]);
    x[3] = padd(t0, t2); x[7] = addmpi(t1, t3);
    x[11] = psub(t0, t2); x[15] = addmni(t1, t3);
  }
#pragma unroll
  for (int q = 0; q < 16; ++q) a[q] = x[q];
}

// apply a[q] *= b^q (CONJ: *= conj(b^q)); tree powers, <=8 live
template <bool CONJ>
__device__ __forceinline__ void tw_pow16(v2f a[16], v2f b) {
  const v2f p2 = cmul(b, b);
  const v2f p3 = cmul(p2, b);
  const v2f p4 = cmul(p2, p2);
  const v2f p5 = cmul(p4, b);
  const v2f p6 = cmul(p4, p2);
  const v2f p7 = cmul(p4, p3);
  const v2f p8 = cmul(p4, p4);
#define APQ(q, p)                         \
  if constexpr (CONJ) a[q] = cmulj(a[q], p); \
  else a[q] = cmul(a[q], p)
  APQ(1, b); APQ(2, p2); APQ(3, p3); APQ(4, p4);
  APQ(5, p5); APQ(6, p6); APQ(7, p7); APQ(8, p8);
  APQ(9, cmul(p8, b)); APQ(10, cmul(p8, p2)); APQ(11, cmul(p8, p3));
  APQ(12, cmul(p8, p4)); APQ(13, cmul(p8, p5)); APQ(14, cmul(p8, p6));
  APQ(15, cmul(p8, p7));
#undef APQ
}

// ---------------- kernel 0: twiddle table tw[j] = e^{-2pi i j/N} ----------------
__global__ __launch_bounds__(256) void build_tw(v2f* __restrict__ twg) {
  const int j = blockIdx.x * 256 + threadIdx.x;
  if (j < NFFT) {
    double ang = (-2.0 * 3.14159265358979323846) * (double)j / (double)NFFT;
    twg[j] = (v2f){(float)cos(ang), (float)sin(ang)};
  }
}

// ---- kernel 1: CgT[q*256+t] = (fwd chain of c at slot q of thread t)/N ----
__global__ __launch_bounds__(256, 2) void build_C(const float* __restrict__ r,
                                                  const v2f* __restrict__ twg,
                                                  v2f* __restrict__ CgT) {
  __shared__ v2f d[PAD(NFFT - 1) + 1];
  const int t = threadIdx.x;
  v2f a[16];
  // F256 from global c[k] = r[(N-k)&mask]
#pragma unroll
  for (int q = 0; q < 16; ++q) {
    const int idx = t + 256 * q;
    a[q] = (v2f){r[(NFFT - idx) & (NFFT - 1)], 0.f};
  }
  fft16(a);
  tw_pow16<false>(a, twg[t]);
#pragma unroll
  for (int q = 0; q < 16; ++q) d[PAD(t + 256 * q)] = a[q];
  __syncthreads();
  // F16
  const int b16 = (t >> 4) * 256 + (t & 15);
#pragma unroll
  for (int q = 0; q < 16; ++q) a[q] = d[PAD(b16 + 16 * q)];
  fft16(a);
  tw_pow16<false>(a, twg[(t & 15) * 16]);
#pragma unroll
  for (int q = 0; q < 16; ++q) d[PAD(b16 + 16 * q)] = a[q];
  __syncthreads();
  // F1 + scale -> CgT (q-major, coalesced)
#pragma unroll
  for (int q = 0; q < 16; ++q) a[q] = d[PAD(16 * t + q)];
  fft16(a);
  const float s = 1.0f / (float)NFFT;
#pragma unroll
  for (int q = 0; q < 16; ++q)
    CgT[q * 256 + t] = (v2f){a[q].x * s, a[q].y * s};
}

// ------ kernel 2: packed 2-row radix-16 FFT conv, direct-global ends ------
__global__ __launch_bounds__(256, 2) void fft_conv10(
    const float* __restrict__ x, const v2f* __restrict__ CgT,
    const v2f* __restrict__ twg, const float* __restrict__ bias,
    float* __restrict__ y) {
  __shared__ v2f d[PAD(NFFT - 1) + 1];
  const int t = threadIdx.x;  // 0..255
  const size_t r0 = 2 * (size_t)blockIdx.x;
  const float* x0 = x + r0 * NFFT;
  const float* x1 = x0 + NFFT;
  float* y0 = y + r0 * NFFT;
  float* y1 = y0 + NFFT;

  v2f a[16];

  // ---- F256 fused with global load (scalar coalesced, verified R15) ----
#pragma unroll
  for (int q = 0; q < 16; ++q)
    a[q] = (v2f){x0[t + 256 * q], x1[t + 256 * q]};
  fft16(a);
  tw_pow16<false>(a, twg[t]);
#pragma unroll
  for (int q = 0; q < 16; ++q) d[PAD(t + 256 * q)] = a[q];
  __syncthreads();

  // ---- F16 ----
  const int b16 = (t >> 4) * 256 + (t & 15);
#pragma unroll
  for (int q = 0; q < 16; ++q) a[q] = d[PAD(b16 + 16 * q)];
  fft16(a);
  tw_pow16<false>(a, twg[(t & 15) * 16]);
#pragma unroll
  for (int q = 0; q < 16; ++q) d[PAD(b16 + 16 * q)] = a[q];
  __syncthreads();

  // ---- fused F1 + pointwise(CgT, pre-scaled 1/N) + I1 ----
#pragma unroll
  for (int q = 0; q < 16; ++q) a[q] = d[PAD(16 * t + q)];
  fft16(a);
#pragma unroll
  for (int q = 0; q < 16; ++q) a[q] = cmul(a[q], CgT[q * 256 + t]);
  ifft16(a);
#pragma unroll
  for (int q = 0; q < 16; ++q) d[PAD(16 * t + q)] = a[q];
  __syncthreads();

  // ---- I16: un-twiddle (conj) then inverse butterfly ----
#pragma unroll
  for (int q = 0; q < 16; ++q) a[q] = d[PAD(b16 + 16 * q)];
  tw_pow16<true>(a, twg[(t & 15) * 16]);
  ifft16(a);
#pragma unroll
  for (int q = 0; q < 16; ++q) d[PAD(b16 + 16 * q)] = a[q];
  __syncthreads();

  // ---- I256 fused with global store + bias ----
#pragma unroll
  for (int q = 0; q < 16; ++q) a[q] = d[PAD(t + 256 * q)];
  tw_pow16<true>(a, twg[t]);
  ifft16(a);
#pragma unroll
  for (int q = 0; q < 16; ++q) {
    const int idx = t + 256 * q;
    const float bv = bias[idx];
    y0[idx] = a[q].x + bv;
    y1[idx] = a[q].y + bv;
  }
}

// ---------------- fallback GEMM (no ws / odd shapes) ----------------

typedef __attribute__((ext_vector_type(8))) short bf16x8;

__device__ __forceinline__ unsigned short f2bf(float f) {
  union { __hip_bfloat16 h; unsigned short u; } v;
  v.h = __float2bfloat16(f);
  return v.u;
}

#define LDP 72

__global__ __launch_bounds__(256) void circ_gemm_fb(
    const float* __restrict__ x, const float* __restrict__ r,
    const float* __restrict__ bias, float* __restrict__ y, int n) {
  __shared__ unsigned short Asf[128][LDP];
  __shared__ unsigned short Bsf[128][LDP];

  const int tid = threadIdx.x;
  const int wid = tid >> 6;
  const int lane = tid & 63;
  const int bm0 = blockIdx.y * 128;
  const int bn0 = blockIdx.x * 128;
  const int m0w = (wid >> 1) * 64;
  const int n0w = (wid & 1) * 64;
  const int lr = lane & 15;
  const int lk = (lane >> 4) * 8;
  const int mask = n - 1;

  f32x4 acc[4][4];
#pragma unroll
  for (int i = 0; i < 4; ++i)
#pragma unroll
    for (int j = 0; j < 4; ++j) acc[i][j] = (f32x4){0.f, 0.f, 0.f, 0.f};

  const int arow = tid >> 4;
  const int acol = (tid & 15) * 4;
  const int bnn = tid >> 1;
  const int bk0 = (tid & 1) * 32;

  for (int k0 = 0; k0 < n; k0 += 64) {
#pragma unroll
    for (int p = 0; p < 8; ++p) {
      const float4 v =
          *(const float4*)&x[(size_t)(bm0 + arow + p * 16) * n + k0 + acol];
      us4 hh;
      hh.x = f2bf(v.x); hh.y = f2bf(v.y); hh.z = f2bf(v.z); hh.w = f2bf(v.w);
      *(us4*)&Asf[arow + p * 16][acol] = hh;
    }
    {
      const int base = k0 + bk0 - bn0 - bnn;
#pragma unroll
      for (int kq = 0; kq < 32; kq += 4) {
        us4 hh;
        hh.x = f2bf(r[(base + kq + 0) & mask]);
        hh.y = f2bf(r[(base + kq + 1) & mask]);
        hh.z = f2bf(r[(base + kq + 2) & mask]);
        hh.w = f2bf(r[(base + kq + 3) & mask]);
        *(us4*)&Bsf[bnn][bk0 + kq] = hh;
      }
    }
    __syncthreads();

#pragma unroll
    for (int kk = 0; kk < 2; ++kk) {
      bf16x8 af[4], bfr[4];
#pragma unroll
      for (int mi = 0; mi < 4; ++mi)
        af[mi] = *(const bf16x8*)&Asf[m0w + mi * 16 + lr][kk * 32 + lk];
#pragma unroll
      for (int ni = 0; ni < 4; ++ni)
        bfr[ni] = *(const bf16x8*)&Bsf[n0w + ni * 16 + lr][kk * 32 + lk];
#pragma unroll
      for (int mi = 0; mi < 4; ++mi)
#pragma unroll
        for (int ni = 0; ni < 4; ++ni)
          acc[mi][ni] = __builtin_amdgcn_mfma_f32_16x16x32_bf16(
              af[mi], bfr[ni], acc[mi][ni], 0, 0, 0);
    }
    __syncthreads();
  }

#pragma unroll
  for (int ni = 0; ni < 4; ++ni) {
    const int col = bn0 + n0w + ni * 16 + lr;
    const float bv = bias[col];
#pragma unroll
    for (int mi = 0; mi < 4; ++mi) {
      const int row0 = bm0 + m0w + mi * 16 + (lane >> 4) * 4;
#pragma unroll
      for (int j = 0; j < 4; ++j)
        y[(size_t)(row0 + j) * n + col] = acc[mi][ni][j] + bv;
    }
  }
}

// ---------------- launch ----------------

extern "C" void kernel_launch(void* const* d_in, const int* in_sizes, int n_in,
                              void* d_out, int out_size, void* d_ws,
                              size_t ws_size, hipStream_t stream) {
  const float* x = (const float*)d_in[0];
  const float* r = (const float*)d_in[1];
  const float* b = (const float*)d_in[2];
  float* y = (float*)d_out;
  const int n = in_sizes[1];          // 4096
  const int batch = in_sizes[0] / n;  // 8192

  if (n == NFFT && (batch & 1) == 0 && ws_size >= 2 * NFFT * sizeof(v2f)) {
    v2f* twg = (v2f*)d_ws;
    v2f* CgT = twg + NFFT;
    build_tw<<<NFFT / 256, 256, 0, stream>>>(twg);
    build_C<<<1, 256, 0, stream>>>(r, twg, CgT);
    fft_conv10<<<batch / 2, 256, 0, stream>>>(x, CgT, twg, b, y);
  } else {
    dim3 grid(n / 128, batch / 128);
    circ_gemm_fb<<<grid, 256, 0, stream>>>(x, r, b, y, n);
  }
}